// Round 4
// baseline (314.180 us; speedup 1.0000x reference)
//
#include <hip/hip_runtime.h>
#include <hip/hip_bf16.h>
#include <math.h>

#define B_  32
#define N_  512
#define C_  384
#define H_  6
#define HD_ 64
#define M_  (B_*N_)   // 16384 rows

typedef __attribute__((ext_vector_type(8))) short bfrag;            // 8 bf16 (4 VGPRs)
typedef __attribute__((ext_vector_type(8))) unsigned short u16x8;   // 8 bf16 loads
typedef __attribute__((ext_vector_type(4))) float f32x4;            // mfma C/D

__device__ __forceinline__ unsigned short f2bfu(float f){
  unsigned int u = __float_as_uint(f);
  u += 0x7fffu + ((u >> 16) & 1u);   // round-to-nearest-even
  return (unsigned short)(u >> 16);
}
__device__ __forceinline__ float bf2f(unsigned short u){
  return __uint_as_float(((unsigned int)u) << 16);
}
__device__ __forceinline__ bfrag cvt8(float4 a, float4 b){
  bfrag r;
  r[0]=(short)f2bfu(a.x); r[1]=(short)f2bfu(a.y); r[2]=(short)f2bfu(a.z); r[3]=(short)f2bfu(a.w);
  r[4]=(short)f2bfu(b.x); r[5]=(short)f2bfu(b.y); r[6]=(short)f2bfu(b.z); r[7]=(short)f2bfu(b.w);
  return r;
}
// async global->LDS, 16B per lane; LDS dest must be wave-uniform base + lane*16
__device__ __forceinline__ void gload_lds16(const unsigned short* gp, unsigned short* lp){
  __builtin_amdgcn_global_load_lds(
      (const __attribute__((address_space(1))) void*)gp,
      (__attribute__((address_space(3))) void*)lp, 16, 0, 0);
}

// ---------------- params ----------------
__global__ void param_kernel(const float* __restrict__ scale_p,
                             const float* __restrict__ power_p,
                             float* __restrict__ scale_inv,
                             float* __restrict__ power){
  int t = threadIdx.x;
  if (t < C_){
    float s  = scale_p[t];
    scale_inv[t] = 1.0f / log1pf(expf(s));   // 1/softplus
  }
  if (t < H_*HD_){
    float p = power_p[t];
    power[t] = 1.0f + 4.0f / (1.0f + expf(-p));
  }
}

__global__ void sentinel_kernel(float* __restrict__ out, int n){
  int i = blockIdx.x*256 + threadIdx.x;
  if (i < n) out[i] = 1.0e9f;
}

// ---------------- bf16 conversion prepass: x, y, W, Wp ----------------
__global__ __launch_bounds__(256) void cvt_bf16_kernel(
    const float* __restrict__ x, const float* __restrict__ y,
    const float* __restrict__ W, const float* __restrict__ Wp,
    unsigned short* __restrict__ xb, unsigned short* __restrict__ yb,
    unsigned short* __restrict__ Wb, unsigned short* __restrict__ Wpb)
{
  const int bid = blockIdx.x;
  const float* src; unsigned short* dst; int base;
  if (bid < 3072)      { src = x;  dst = xb;  base = bid; }
  else if (bid < 6144) { src = y;  dst = yb;  base = bid - 3072; }
  else if (bid < 6432) { src = W;  dst = Wb;  base = bid - 6144; }
  else                 { src = Wp; dst = Wpb; base = bid - 6432; }
  const size_t i0 = ((size_t)base*256 + threadIdx.x)*8;
  float4 a = *reinterpret_cast<const float4*>(src + i0);
  float4 b = *reinterpret_cast<const float4*>(src + i0 + 4);
  *reinterpret_cast<bfrag*>(dst + i0) = cvt8(a, b);
}

// ---------------- fused qkvg GEMM: [16384 x 1536] = A_mode @ Wb^T, bf16 MFMA ----------------
// grid (12, 128): col block 0..11 (mode = bx/3), row block 0..127.
// Modes 0/1: epilogue applies scale (+pe) + power map, restages through LDS
// (quad-XOR block swizzle) and writes qf/kf [B,N,H,128] with coalesced u16x8 rows.
__global__ __launch_bounds__(256) void gemm_qkvg(
    const unsigned short* __restrict__ xb, const unsigned short* __restrict__ yb,
    const unsigned short* __restrict__ Wb, const float* __restrict__ bias,
    const float* __restrict__ pe, const float* __restrict__ scale_inv,
    const float* __restrict__ power,
    unsigned short* __restrict__ qf, unsigned short* __restrict__ kf,
    unsigned short* __restrict__ v, unsigned short* __restrict__ g)
{
  __shared__ __align__(16) unsigned short smem[16384];  // 32KB: As[2][4096] | Bs[2][4096]; reused by epilogue

  const int tid  = threadIdx.x;
  const int row0 = blockIdx.y * 128;
  const int col0 = blockIdx.x * 128;       // global col in [0,1536)
  const int mode = blockIdx.x / 3;         // 0:q(y) 1:k 2:v 3:g
  const unsigned short* Ab = (mode == 0) ? yb : xb;

  const int wave = tid >> 6, lane = tid & 63;
  const int wm = (wave >> 1) * 64, wn = (wave & 1) * 64;
  const int fr = lane & 15, quad = lane >> 4;
  const int srr = tid >> 2;                // staging row 0..63
  const int skc = (tid & 3) * 8;           // staging col 0,8,16,24

  const unsigned short* ga0 = &Ab[(size_t)(row0 + srr)*C_ + skc];
  const unsigned short* gb0 = &Wb[(size_t)(col0 + srr)*C_ + skc];
  const size_t gstep = (size_t)64*C_;

  f32x4 acc[4][4] = {};

  // prologue: stage k0=0 into buffer 0
  gload_lds16(ga0,         &smem[tid*8]);
  gload_lds16(ga0 + gstep, &smem[2048 + tid*8]);
  gload_lds16(gb0,         &smem[8192 + tid*8]);
  gload_lds16(gb0 + gstep, &smem[8192 + 2048 + tid*8]);
  __syncthreads();   // drains vmcnt -> buffer 0 ready

  #pragma unroll 2
  for (int t = 0; t < 12; t++){
    const int cur = t & 1;
    if (t < 11){
      const int k0 = (t+1)*32;
      const int nxt = cur^1;
      gload_lds16(ga0 + k0,         &smem[nxt*4096 + tid*8]);
      gload_lds16(ga0 + gstep + k0, &smem[nxt*4096 + 2048 + tid*8]);
      gload_lds16(gb0 + k0,         &smem[8192 + nxt*4096 + tid*8]);
      gload_lds16(gb0 + gstep + k0, &smem[8192 + nxt*4096 + 2048 + tid*8]);
    }
    bfrag af[4], bf[4];
    #pragma unroll
    for (int f = 0; f < 4; f++){
      af[f] = *reinterpret_cast<const bfrag*>(&smem[cur*4096 + (wm + f*16 + fr)*32 + quad*8]);
      bf[f] = *reinterpret_cast<const bfrag*>(&smem[8192 + cur*4096 + (wn + f*16 + fr)*32 + quad*8]);
    }
    #pragma unroll
    for (int i=0;i<4;i++)
      #pragma unroll
      for (int j=0;j<4;j++)
        acc[i][j] = __builtin_amdgcn_mfma_f32_16x16x32_bf16(af[i], bf[j], acc[i][j], 0, 0, 0);
    __syncthreads();   // drains vmcnt (prefetch landed) + all waves done reading cur
  }

  // epilogue (mode uniform per block)
  const int cbase = col0 - mode*384;
  if (mode <= 1){
    // LDS restage: 2 passes of 64 rows; tile [64 rows][256 feats] bf16 = 32KB
    unsigned short* dst = (mode == 0) ? qf : kf;
    const int hh0 = cbase >> 6;            // first head covered (block covers hh0, hh0+1)
    for (int pass = 0; pass < 2; pass++){
      if ((wave >> 1) == pass){
        const int swz = quad << 3;         // XOR feat bits 3,4 by quad (row-determined)
        #pragma unroll
        for (int i = 0; i < 4; i++){
          const int rloc = i*16 + quad*4;  // local row base 0..63
          #pragma unroll
          for (int j = 0; j < 4; j++){
            const int cl = wn + j*16 + fr; // 0..127
            const int hl = cl >> 6, dd = cl & 63;
            const int cc = cbase + cl;
            const float bcol = bias[mode*384 + cc];
            const float scv  = scale_inv[cc];
            const float p    = power[cc];
            const int fpos = (hl*128 + dd) ^ swz;   // swz < 64, +64 commutes with ^
            #pragma unroll
            for (int r = 0; r < 4; r++){
              const int row = row0 + pass*64 + rloc + r;
              float val = acc[i][j][r] + bcol;
              if (mode == 1) val += pe[(row & (N_-1))*C_ + cc];
              val *= scv;
              const float ax = fabsf(val);
              const float pv = (ax > 0.0f) ? exp2f(p * log2f(ax)) : 0.0f;
              smem[(rloc + r)*256 + fpos]      = f2bfu((val > 0.0f) ? pv : 0.0f);
              smem[(rloc + r)*256 + fpos + 64] = f2bfu((val < 0.0f) ? pv : 0.0f);
            }
          }
        }
      }
      __syncthreads();
      // consumer: coalesced u16x8 rows -> global
      #pragma unroll
      for (int it = 0; it < 8; it++){
        const int idx = it*256 + tid;           // 0..2047
        const int rl = idx >> 5, cb = idx & 31; // row 0..63, feat-block 0..31
        const int bswz = (rl >> 2) & 3;
        u16x8 val = *reinterpret_cast<const u16x8*>(&smem[rl*256 + ((cb ^ bswz) << 3)]);
        *reinterpret_cast<u16x8*>(&dst[(size_t)(row0 + pass*64 + rl)*768 + hh0*128 + cb*8]) = val;
      }
      __syncthreads();   // before next pass producers overwrite
    }
  } else {
    unsigned short* dst = (mode == 2) ? v : g;
    #pragma unroll
    for (int i = 0; i < 4; i++){
      const int rowb = row0 + wm + i*16 + quad*4;
      #pragma unroll
      for (int j = 0; j < 4; j++){
        const int cc = cbase + wn + j*16 + fr;
        const float bcol = bias[mode*384 + cc];
        #pragma unroll
        for (int r = 0; r < 4; r++)
          dst[(size_t)(rowb + r)*C_ + cc] = f2bfu(acc[i][j][r] + bcol);
      }
    }
  }
}

// ---------------- attention, MFMA: one block per (b,h), 512 threads (8 waves) ----------------
// qf/kf are precomputed bf16 feature maps [B,N,H,128]; phase-A LDS uses XOR col swizzle.
#define NC_ 256
__global__ __launch_bounds__(512) void attn_kernel(
    const unsigned short* __restrict__ qf, const unsigned short* __restrict__ kf,
    const unsigned short* __restrict__ v, float* __restrict__ xa)
{
  const int bh = blockIdx.x;
  const int b = bh / H_, h = bh % H_;
  __shared__ __align__(16) unsigned short smem[54912];  // 109,824 B
  unsigned short* kfT  = smem;                  // [128][264] phase A (col-swizzled)
  unsigned short* vT   = smem + 33792;          // [80][264]  phase A (col-swizzled)
  unsigned short* kvBT = smem;                  // [80][136]  phase B (alias)
  unsigned short* qs   = smem + 33792;          // [128][136] phase B (alias)

  const int tid = threadIdx.x;
  const int wave = tid >> 6, lane = tid & 63;
  const int fr = lane & 15, quad = lane >> 4;

  const unsigned short* kfg   = kf + (size_t)b*N_*768 + h*128;
  const unsigned short* vbase = v  + (size_t)b*N_*C_  + h*HD_;

  // init vT rows 64..79 (ones column + zeros) — constant rows, swizzle-invariant
  for (int i = tid; i < 16*NC_; i += 512){
    int e = 64 + (i >> 8);
    int nl = i & (NC_-1);
    vT[e*264 + nl] = (e == 64) ? (unsigned short)0x3F80 : (unsigned short)0;
  }
  __syncthreads();

  f32x4 acc[5] = {};
  for (int chunk = 0; chunk < 2; chunk++){
    const int n0 = chunk * NC_;
    // kf: 128 c x 256 nl transpose-copy; store col = nl ^ ((c>>3)<<3)
    for (int it = 0; it < 8; it++){
      int flat = it*512 + tid;
      int cg = flat & 15, nl = flat >> 4;
      int swz = cg << 3;
      u16x8 k8 = *reinterpret_cast<const u16x8*>(&kfg[(size_t)(n0+nl)*768 + cg*8]);
      #pragma unroll
      for (int j = 0; j < 8; j++) kfT[(cg*8+j)*264 + (nl ^ swz)] = k8[j];
    }
    // v: 64 c x 256 nl
    for (int it = 0; it < 4; it++){
      int flat = it*512 + tid;
      int cg = flat & 7, nl = flat >> 3;
      int swz = cg << 3;
      u16x8 v8 = *reinterpret_cast<const u16x8*>(&vbase[(size_t)(n0+nl)*C_ + cg*8]);
      #pragma unroll
      for (int j = 0; j < 8; j++) vT[(cg*8+j)*264 + (nl ^ swz)] = v8[j];
    }
    __syncthreads();
    const int arow = wave*16 + fr;
    const int aswz = (arow >> 3) << 3;
    for (int kk = 0; kk < NC_/32; kk++){
      int ko = kk*32 + quad*8;
      bfrag af = *reinterpret_cast<const bfrag*>(&kfT[arow*264 + (ko ^ aswz)]);
      #pragma unroll
      for (int j = 0; j < 5; j++){
        const int brow = j*16 + fr;
        const int bswz = (brow >> 3) << 3;
        bfrag bfr = *reinterpret_cast<const bfrag*>(&vT[brow*264 + (ko ^ bswz)]);
        acc[j] = __builtin_amdgcn_mfma_f32_16x16x32_bf16(af, bfr, acc[j], 0, 0, 0);
      }
    }
    __syncthreads();
  }

  // write kvBT (scaled), with d^64 flip for e>=32; rows 64/65 = z-vectors
  const float invN = 1.0f / (float)N_;
  {
    const int dbase = wave*16 + quad*4;
    #pragma unroll
    for (int j = 0; j < 4; j++){
      const int e = j*16 + fr;
      const int dd = (e < 32) ? dbase : (dbase ^ 64);
      ushort4 w4;
      w4.x = f2bfu(acc[j][0] * invN);
      w4.y = f2bfu(acc[j][1] * invN);
      w4.z = f2bfu(acc[j][2] * invN);
      w4.w = f2bfu(acc[j][3] * invN);
      *reinterpret_cast<ushort4*>(&kvBT[e*136 + dd]) = w4;
    }
    if (fr == 0){
      ushort4 wk;
      wk.x = f2bfu(acc[4][0] * invN);
      wk.y = f2bfu(acc[4][1] * invN);
      wk.z = f2bfu(acc[4][2] * invN);
      wk.w = f2bfu(acc[4][3] * invN);
      *reinterpret_cast<ushort4*>(&kvBT[64*136 + dbase]) = wk;          // km[d]
      *reinterpret_cast<ushort4*>(&kvBT[65*136 + (dbase^64)]) = wk;     // km at flipped d
    }
  }
  __syncthreads();

  // phase B: 4 m-chunks of 128 rows (qf staging = pure vector copy)
  const unsigned short* qfg = qf + (size_t)b*N_*768 + h*128;
  float* xabase = xa + (size_t)b*N_*C_ + h*HD_;
  for (int mc = 0; mc < 4; mc++){
    const int m0 = mc * 128;
    for (int it = 0; it < 4; it++){
      int flat = it*512 + tid;
      int cg = flat & 15, nl = flat >> 4;
      *reinterpret_cast<u16x8*>(&qs[nl*136 + cg*8]) =
          *reinterpret_cast<const u16x8*>(&qfg[(size_t)(m0+nl)*768 + cg*8]);
    }
    __syncthreads();
    f32x4 a2[5] = {};
    for (int kk = 0; kk < 4; kk++){
      int ko = kk*32 + quad*8;
      bfrag af = *reinterpret_cast<const bfrag*>(&qs[(wave*16 + fr)*136 + ko]);
      #pragma unroll
      for (int j = 0; j < 5; j++){
        bfrag bfr = *reinterpret_cast<const bfrag*>(&kvBT[(j*16 + fr)*136 + ko]);
        a2[j] = __builtin_amdgcn_mfma_f32_16x16x32_bf16(af, bfr, a2[j], 0, 0, 0);
      }
    }
    #pragma unroll
    for (int r = 0; r < 4; r++){
      const float zsim = __shfl(a2[4][r], quad*16);
      const float zopp = __shfl(a2[4][r], quad*16 + 1);
      const int n = m0 + wave*16 + quad*4 + r;
      #pragma unroll
      for (int j = 0; j < 4; j++){
        const int e = j*16 + fr;
        const float z = (e < 32) ? zsim : zopp;
        xabase[(size_t)n*C_ + e] = a2[j][r] / (z + 1e-6f);
      }
    }
    __syncthreads();   // before next m-chunk overwrites qs
  }
}

// ---------------- conv: 16 ch/block (grid 192x4, 3 blocks/CU), fuses (xa+vc)*g -> ab bf16 ----------------
__global__ __launch_bounds__(512) void conv_kernel(
    const unsigned short* __restrict__ v, const float* __restrict__ dwc_w,
    const float* __restrict__ dwc_b, const float* __restrict__ xa,
    const unsigned short* __restrict__ g, unsigned short* __restrict__ ab)
{
  const int bh = blockIdx.x;
  const int b = bh / H_, h = bh % H_;
  const int ch0 = blockIdx.y * 16;
  __shared__ float vol[16][521];   // 33.3 KB
  __shared__ float wv[16][126];    // 8.1 KB
  __shared__ float wb[16];
  const int tid = threadIdx.x;
  const unsigned short* vbase = v + (size_t)b*N_*C_ + h*HD_;
  const float* xabatch = xa + (size_t)b*N_*C_ + (size_t)h*N_*HD_;
  const unsigned short* gb = g + (size_t)b*N_*C_ + (size_t)h*N_*HD_;
  unsigned short* abb = ab + (size_t)b*N_*C_ + (size_t)h*N_*HD_;

  // stage v: 16 ch x 512 n
  for (int it = 0; it < 16; it++){
    int flat = it*512 + tid;
    int cl = flat & 15, n = flat >> 4;
    vol[cl][n] = bf2f(vbase[(size_t)n*C_ + ch0 + cl]);
  }
  for (int i = tid; i < 16*125; i += 512){
    int ch = i / 125, wi = i - ch*125;
    wv[ch][wi] = dwc_w[(ch0+ch)*125 + wi];
  }
  if (tid < 16) wb[tid] = dwc_b[ch0 + tid];
  __syncthreads();

  for (int t = 0; t < 2; t++){
    const int task = t*512 + tid;
    const int ch = task & 15;
    const int zy = task >> 4;          // 0..63
    const int z = zy >> 3, yc = zy & 7;
    float o[8];
    const float bias = wb[ch];
    #pragma unroll
    for (int xx = 0; xx < 8; xx++) o[xx] = bias;
    #pragma unroll
    for (int kd = 0; kd < 5; kd++){
      const int zz = z + kd - 2;
      if ((unsigned)zz >= 8u) continue;
      #pragma unroll
      for (int kh = 0; kh < 5; kh++){
        const int yy = yc + kh - 2;
        if ((unsigned)yy >= 8u) continue;
        const float* row = &vol[ch][zz*64 + yy*8];
        float rr[8];
        #pragma unroll
        for (int xx = 0; xx < 8; xx++) rr[xx] = row[xx];
        const float* wrow = &wv[ch][kd*25 + kh*5];
        float w5[5];
        #pragma unroll
        for (int kw = 0; kw < 5; kw++) w5[kw] = wrow[kw];
        #pragma unroll
        for (int xx = 0; xx < 8; xx++){
          #pragma unroll
          for (int kw = 0; kw < 5; kw++){
            const int xi = xx + kw - 2;
            if ((unsigned)xi < 8u) o[xx] = fmaf(w5[kw], rr[xi], o[xx]);
          }
        }
      }
    }
    const int nb = zy * 8;
    #pragma unroll
    for (int xx = 0; xx < 8; xx++){
      const size_t di = (size_t)(nb + xx)*HD_ + ch0 + ch;
      abb[di] = f2bfu((xabatch[di] + o[xx]) * bf2f(gb[di]));   // coalesced (ch fastest)
    }
  }
}

// ---------------- proj GEMM: m97 structure over bf16 ab/Wpb ----------------
__global__ __launch_bounds__(256) void proj_kernel(
    const unsigned short* __restrict__ ab, const unsigned short* __restrict__ Wpb,
    const float* __restrict__ bp, float* __restrict__ out)
{
  __shared__ unsigned short As[2][4096];
  __shared__ unsigned short Bs[2][4096];

  const int tid  = threadIdx.x;
  const int row0 = blockIdx.y * 128;
  const int col0 = blockIdx.x * 128;
  const int wave = tid >> 6, lane = tid & 63;
  const int wm = (wave >> 1) * 64, wn = (wave & 1) * 64;
  const int fr = lane & 15, quad = lane >> 4;
  const int srr = tid >> 2;
  const int skc = (tid & 3) * 8;

  const unsigned short* ga0 = &ab[(size_t)(row0 + srr)*C_ + skc];
  const unsigned short* gb0 = &Wpb[(size_t)(col0 + srr)*C_ + skc];
  const size_t gstep = (size_t)64*C_;

  f32x4 acc[4][4] = {};

  gload_lds16(ga0,         &As[0][tid*8]);
  gload_lds16(ga0 + gstep, &As[0][2048 + tid*8]);
  gload_lds16(gb0,         &Bs[0][tid*8]);
  gload_lds16(gb0 + gstep, &Bs[0][2048 + tid*8]);
  __syncthreads();

  #pragma unroll 2
  for (int t = 0; t < 12; t++){
    const int cur = t & 1;
    if (t < 11){
      const int k0 = (t+1)*32;
      gload_lds16(ga0 + k0,         &As[cur^1][tid*8]);
      gload_lds16(ga0 + gstep + k0, &As[cur^1][2048 + tid*8]);
      gload_lds16(gb0 + k0,         &Bs[cur^1][tid*8]);
      gload_lds16(gb0 + gstep + k0, &Bs[cur^1][2048 + tid*8]);
    }
    bfrag af[4], bf[4];
    #pragma unroll
    for (int f = 0; f < 4; f++){
      af[f] = *reinterpret_cast<const bfrag*>(&As[cur][(wm + f*16 + fr)*32 + quad*8]);
      bf[f] = *reinterpret_cast<const bfrag*>(&Bs[cur][(wn + f*16 + fr)*32 + quad*8]);
    }
    #pragma unroll
    for (int i=0;i<4;i++)
      #pragma unroll
      for (int j=0;j<4;j++)
        acc[i][j] = __builtin_amdgcn_mfma_f32_16x16x32_bf16(af[i], bf[j], acc[i][j], 0, 0, 0);
    __syncthreads();
  }

  #pragma unroll
  for (int i = 0; i < 4; i++){
    const int rowb = row0 + wm + i*16 + quad*4;
    #pragma unroll
    for (int j = 0; j < 4; j++){
      const int col = col0 + wn + j*16 + fr;
      const float bcol = bp[col];
      #pragma unroll
      for (int r = 0; r < 4; r++)
        out[(size_t)(rowb + r)*C_ + col] = acc[i][j][r] + bcol;
    }
  }
}

extern "C" void kernel_launch(void* const* d_in, const int* in_sizes, int n_in,
                              void* d_out, int out_size, void* d_ws, size_t ws_size,
                              hipStream_t stream){
  float* out = (float*)d_out;

  const int expect[11] = {6291456, 6291456, 589824, 1536, 147456, 384, 8000, 64, 384, 384, 196608};
  bool ok = (n_in == 11);
  for (int i = 0; ok && i < 11; i++) ok = (in_sizes[i] == expect[i]);
  if (!ok){
    sentinel_kernel<<<(out_size+255)/256, 256, 0, stream>>>(out, out_size);
    return;
  }

  const float* x    = (const float*)d_in[0];
  const float* y    = (const float*)d_in[1];
  const float* W    = (const float*)d_in[2];
  const float* bq   = (const float*)d_in[3];
  const float* Wp   = (const float*)d_in[4];
  const float* bp   = (const float*)d_in[5];
  const float* dwcw = (const float*)d_in[6];
  const float* dwcb = (const float*)d_in[7];
  const float* pwp  = (const float*)d_in[8];
  const float* scp  = (const float*)d_in[9];
  const float* pe   = (const float*)d_in[10];

  float* ws = (float*)d_ws;
  const size_t SZ = (size_t)M_ * C_;   // 6,291,456
  // Lifetime-aliased layout (float units). qf/kf are M*768 ushorts = SZ floats EACH.
  //   qf  [0, SZ)          (2*SZ ushorts)        — dead after attn
  //   kf  [SZ, 2SZ)        (2*SZ ushorts)        — dead after attn
  //   v   [2SZ, 2.5SZ)     (SZ ushorts)
  //   g   [2.5SZ, 3SZ)     (SZ ushorts)
  //   xb  [3SZ, 3.5SZ) yb [3.5SZ, 4SZ)           — dead after gemm
  //   xa  [3SZ, 4SZ) f32                         — aliases xb/yb, written by attn
  //   ab  [0, 0.5SZ)       (SZ ushorts)          — aliases qf, written by conv
  //   Wb  [4SZ, +294912) Wpb (+73728) params
  unsigned short* qf  = (unsigned short*)ws;              // 2*SZ ushorts
  unsigned short* kfb = qf + 2*SZ;                        // 2*SZ ushorts
  unsigned short* v   = (unsigned short*)(ws + 2*SZ);     // SZ ushorts
  unsigned short* g   = v + SZ;                           // SZ ushorts
  unsigned short* xb  = (unsigned short*)(ws + 3*SZ);     // SZ ushorts
  unsigned short* yb  = xb + SZ;                          // SZ ushorts
  float* xa = ws + 3*SZ;                                  // aliases xb/yb (post-gemm)
  unsigned short* ab  = (unsigned short*)ws;              // aliases qf (post-attn)
  unsigned short* Wb  = (unsigned short*)(ws + 4*SZ);     // 589824 ushorts
  unsigned short* Wpb = Wb + 589824;                      // 147456 ushorts
  float* scale_inv = (float*)(Wpb + 147456);
  float* power     = scale_inv + 512;

  param_kernel<<<1, 512, 0, stream>>>(scp, pwp, scale_inv, power);
  cvt_bf16_kernel<<<6504, 256, 0, stream>>>(x, y, W, Wp, xb, yb, Wb, Wpb);
  gemm_qkvg<<<dim3(12, 128), 256, 0, stream>>>(xb, yb, Wb, bq, pe, scale_inv, power, qf, kfb, v, g);
  attn_kernel<<<dim3(B_*H_), 512, 0, stream>>>(qf, kfb, v, xa);
  conv_kernel<<<dim3(B_*H_, 4), 512, 0, stream>>>(v, dwcw, dwcb, xa, g, ab);
  proj_kernel<<<dim3(3, 128), 256, 0, stream>>>(ab, Wpb, bp, out);
}

// Round 5
// 310.732 us; speedup vs baseline: 1.0111x; 1.0111x over previous
//
#include <hip/hip_runtime.h>
#include <hip/hip_bf16.h>
#include <math.h>

#define B_  32
#define N_  512
#define C_  384
#define H_  6
#define HD_ 64
#define M_  (B_*N_)   // 16384 rows

typedef __attribute__((ext_vector_type(8))) short bfrag;            // 8 bf16 (4 VGPRs)
typedef __attribute__((ext_vector_type(8))) unsigned short u16x8;   // 8 bf16 loads
typedef __attribute__((ext_vector_type(4))) float f32x4;            // mfma C/D

__device__ __forceinline__ unsigned short f2bfu(float f){
  unsigned int u = __float_as_uint(f);
  u += 0x7fffu + ((u >> 16) & 1u);   // round-to-nearest-even
  return (unsigned short)(u >> 16);
}
__device__ __forceinline__ float bf2f(unsigned short u){
  return __uint_as_float(((unsigned int)u) << 16);
}
__device__ __forceinline__ bfrag cvt8(float4 a, float4 b){
  bfrag r;
  r[0]=(short)f2bfu(a.x); r[1]=(short)f2bfu(a.y); r[2]=(short)f2bfu(a.z); r[3]=(short)f2bfu(a.w);
  r[4]=(short)f2bfu(b.x); r[5]=(short)f2bfu(b.y); r[6]=(short)f2bfu(b.z); r[7]=(short)f2bfu(b.w);
  return r;
}
// async global->LDS, 16B per lane; LDS dest must be wave-uniform base + lane*16
__device__ __forceinline__ void gload_lds16(const unsigned short* gp, unsigned short* lp){
  __builtin_amdgcn_global_load_lds(
      (const __attribute__((address_space(1))) void*)gp,
      (__attribute__((address_space(3))) void*)lp, 16, 0, 0);
}

// ---------------- params ----------------
__global__ void param_kernel(const float* __restrict__ scale_p,
                             const float* __restrict__ power_p,
                             float* __restrict__ scale_inv,
                             float* __restrict__ power){
  int t = threadIdx.x;
  if (t < C_){
    float s  = scale_p[t];
    scale_inv[t] = 1.0f / log1pf(expf(s));   // 1/softplus
  }
  if (t < H_*HD_){
    float p = power_p[t];
    power[t] = 1.0f + 4.0f / (1.0f + expf(-p));
  }
}

__global__ void sentinel_kernel(float* __restrict__ out, int n){
  int i = blockIdx.x*256 + threadIdx.x;
  if (i < n) out[i] = 1.0e9f;
}

// ---------------- bf16 conversion prepass: x, y, W, Wp ----------------
__global__ __launch_bounds__(256) void cvt_bf16_kernel(
    const float* __restrict__ x, const float* __restrict__ y,
    const float* __restrict__ W, const float* __restrict__ Wp,
    unsigned short* __restrict__ xb, unsigned short* __restrict__ yb,
    unsigned short* __restrict__ Wb, unsigned short* __restrict__ Wpb)
{
  const int bid = blockIdx.x;
  const float* src; unsigned short* dst; int base;
  if (bid < 3072)      { src = x;  dst = xb;  base = bid; }
  else if (bid < 6144) { src = y;  dst = yb;  base = bid - 3072; }
  else if (bid < 6432) { src = W;  dst = Wb;  base = bid - 6144; }
  else                 { src = Wp; dst = Wpb; base = bid - 6432; }
  const size_t i0 = ((size_t)base*256 + threadIdx.x)*8;
  float4 a = *reinterpret_cast<const float4*>(src + i0);
  float4 b = *reinterpret_cast<const float4*>(src + i0 + 4);
  *reinterpret_cast<bfrag*>(dst + i0) = cvt8(a, b);
}

// ---------------- fused qkvg GEMM: [16384 x 1536] = A_mode @ Wb^T, bf16 MFMA ----------------
// grid (12, 128): col block 0..11 (mode = bx/3), row block 0..127.
// Modes 0/1: epilogue applies scale (+pe) + power map, restages through LDS
// (quad-XOR block swizzle) and writes qf/kf [B,N,H,128] with coalesced u16x8 rows.
// __launch_bounds__(256,4) is REQUIRED: without the cap the allocator hits 140
// VGPR -> 2 waves/SIMD -> latency collapse (r4: 147us vs 71.6us).
__global__ __launch_bounds__(256,4) void gemm_qkvg(
    const unsigned short* __restrict__ xb, const unsigned short* __restrict__ yb,
    const unsigned short* __restrict__ Wb, const float* __restrict__ bias,
    const float* __restrict__ pe, const float* __restrict__ scale_inv,
    const float* __restrict__ power,
    unsigned short* __restrict__ qf, unsigned short* __restrict__ kf,
    unsigned short* __restrict__ v, unsigned short* __restrict__ g)
{
  __shared__ __align__(16) unsigned short smem[16384];  // 32KB: As[2][4096] | Bs[2][4096]; reused by epilogue

  const int tid  = threadIdx.x;
  const int row0 = blockIdx.y * 128;
  const int col0 = blockIdx.x * 128;       // global col in [0,1536)
  const int mode = blockIdx.x / 3;         // 0:q(y) 1:k 2:v 3:g
  const unsigned short* Ab = (mode == 0) ? yb : xb;

  const int wave = tid >> 6, lane = tid & 63;
  const int wm = (wave >> 1) * 64, wn = (wave & 1) * 64;
  const int fr = lane & 15, quad = lane >> 4;
  const int srr = tid >> 2;                // staging row 0..63
  const int skc = (tid & 3) * 8;           // staging col 0,8,16,24

  const unsigned short* ga0 = &Ab[(size_t)(row0 + srr)*C_ + skc];
  const unsigned short* gb0 = &Wb[(size_t)(col0 + srr)*C_ + skc];
  const size_t gstep = (size_t)64*C_;

  f32x4 acc[4][4] = {};

  // prologue: stage k0=0 into buffer 0
  gload_lds16(ga0,         &smem[tid*8]);
  gload_lds16(ga0 + gstep, &smem[2048 + tid*8]);
  gload_lds16(gb0,         &smem[8192 + tid*8]);
  gload_lds16(gb0 + gstep, &smem[8192 + 2048 + tid*8]);
  __syncthreads();   // drains vmcnt -> buffer 0 ready

  #pragma unroll 2
  for (int t = 0; t < 12; t++){
    const int cur = t & 1;
    if (t < 11){
      const int k0 = (t+1)*32;
      const int nxt = cur^1;
      gload_lds16(ga0 + k0,         &smem[nxt*4096 + tid*8]);
      gload_lds16(ga0 + gstep + k0, &smem[nxt*4096 + 2048 + tid*8]);
      gload_lds16(gb0 + k0,         &smem[8192 + nxt*4096 + tid*8]);
      gload_lds16(gb0 + gstep + k0, &smem[8192 + nxt*4096 + 2048 + tid*8]);
    }
    bfrag af[4], bf[4];
    #pragma unroll
    for (int f = 0; f < 4; f++){
      af[f] = *reinterpret_cast<const bfrag*>(&smem[cur*4096 + (wm + f*16 + fr)*32 + quad*8]);
      bf[f] = *reinterpret_cast<const bfrag*>(&smem[8192 + cur*4096 + (wn + f*16 + fr)*32 + quad*8]);
    }
    #pragma unroll
    for (int i=0;i<4;i++)
      #pragma unroll
      for (int j=0;j<4;j++)
        acc[i][j] = __builtin_amdgcn_mfma_f32_16x16x32_bf16(af[i], bf[j], acc[i][j], 0, 0, 0);
    __syncthreads();   // drains vmcnt (prefetch landed) + all waves done reading cur
  }

  // epilogue (mode uniform per block)
  const int cbase = col0 - mode*384;
  if (mode <= 1){
    // LDS restage: 2 passes of 64 rows; tile [64 rows][256 feats] bf16 = 32KB
    unsigned short* dst = (mode == 0) ? qf : kf;
    const int hh0 = cbase >> 6;            // first head covered (block covers hh0, hh0+1)
    for (int pass = 0; pass < 2; pass++){
      if ((wave >> 1) == pass){
        const int swz = quad << 3;         // XOR feat bits 3,4 by quad (row-determined)
        #pragma unroll
        for (int i = 0; i < 4; i++){
          const int rloc = i*16 + quad*4;  // local row base 0..63
          #pragma unroll
          for (int j = 0; j < 4; j++){
            const int cl = wn + j*16 + fr; // 0..127
            const int hl = cl >> 6, dd = cl & 63;
            const int cc = cbase + cl;
            const float bcol = bias[mode*384 + cc];
            const float scv  = scale_inv[cc];
            const float p    = power[cc];
            const int fpos = (hl*128 + dd) ^ swz;   // swz < 64, +64 commutes with ^
            #pragma unroll
            for (int r = 0; r < 4; r++){
              const int row = row0 + pass*64 + rloc + r;
              float val = acc[i][j][r] + bcol;
              if (mode == 1) val += pe[(row & (N_-1))*C_ + cc];
              val *= scv;
              const float ax = fabsf(val);
              const float pv = (ax > 0.0f) ? exp2f(p * log2f(ax)) : 0.0f;
              smem[(rloc + r)*256 + fpos]      = f2bfu((val > 0.0f) ? pv : 0.0f);
              smem[(rloc + r)*256 + fpos + 64] = f2bfu((val < 0.0f) ? pv : 0.0f);
            }
          }
        }
      }
      __syncthreads();
      // consumer: coalesced u16x8 rows -> global
      #pragma unroll
      for (int it = 0; it < 8; it++){
        const int idx = it*256 + tid;           // 0..2047
        const int rl = idx >> 5, cb = idx & 31; // row 0..63, feat-block 0..31
        const int bswz = (rl >> 2) & 3;
        u16x8 val = *reinterpret_cast<const u16x8*>(&smem[rl*256 + ((cb ^ bswz) << 3)]);
        *reinterpret_cast<u16x8*>(&dst[(size_t)(row0 + pass*64 + rl)*768 + hh0*128 + cb*8]) = val;
      }
      __syncthreads();   // before next pass producers overwrite
    }
  } else {
    unsigned short* dst = (mode == 2) ? v : g;
    #pragma unroll
    for (int i = 0; i < 4; i++){
      const int rowb = row0 + wm + i*16 + quad*4;
      #pragma unroll
      for (int j = 0; j < 4; j++){
        const int cc = cbase + wn + j*16 + fr;
        const float bcol = bias[mode*384 + cc];
        #pragma unroll
        for (int r = 0; r < 4; r++)
          dst[(size_t)(rowb + r)*C_ + cc] = f2bfu(acc[i][j][r] + bcol);
      }
    }
  }
}

// ---------------- attention, MFMA: one block per (b,h), 512 threads (8 waves) ----------------
// qf/kf are precomputed bf16 feature maps [B,N,H,128]; phase-A LDS uses XOR col swizzle.
#define NC_ 256
__global__ __launch_bounds__(512) void attn_kernel(
    const unsigned short* __restrict__ qf, const unsigned short* __restrict__ kf,
    const unsigned short* __restrict__ v, float* __restrict__ xa)
{
  const int bh = blockIdx.x;
  const int b = bh / H_, h = bh % H_;
  __shared__ __align__(16) unsigned short smem[54912];  // 109,824 B
  unsigned short* kfT  = smem;                  // [128][264] phase A (col-swizzled)
  unsigned short* vT   = smem + 33792;          // [80][264]  phase A (col-swizzled)
  unsigned short* kvBT = smem;                  // [80][136]  phase B (alias)
  unsigned short* qs   = smem + 33792;          // [128][136] phase B (alias)

  const int tid = threadIdx.x;
  const int wave = tid >> 6, lane = tid & 63;
  const int fr = lane & 15, quad = lane >> 4;

  const unsigned short* kfg   = kf + (size_t)b*N_*768 + h*128;
  const unsigned short* vbase = v  + (size_t)b*N_*C_  + h*HD_;

  // init vT rows 64..79 (ones column + zeros) — constant rows, swizzle-invariant
  for (int i = tid; i < 16*NC_; i += 512){
    int e = 64 + (i >> 8);
    int nl = i & (NC_-1);
    vT[e*264 + nl] = (e == 64) ? (unsigned short)0x3F80 : (unsigned short)0;
  }
  __syncthreads();

  f32x4 acc[5] = {};
  for (int chunk = 0; chunk < 2; chunk++){
    const int n0 = chunk * NC_;
    // kf: 128 c x 256 nl transpose-copy; store col = nl ^ ((c>>3)<<3)
    for (int it = 0; it < 8; it++){
      int flat = it*512 + tid;
      int cg = flat & 15, nl = flat >> 4;
      int swz = cg << 3;
      u16x8 k8 = *reinterpret_cast<const u16x8*>(&kfg[(size_t)(n0+nl)*768 + cg*8]);
      #pragma unroll
      for (int j = 0; j < 8; j++) kfT[(cg*8+j)*264 + (nl ^ swz)] = k8[j];
    }
    // v: 64 c x 256 nl
    for (int it = 0; it < 4; it++){
      int flat = it*512 + tid;
      int cg = flat & 7, nl = flat >> 3;
      int swz = cg << 3;
      u16x8 v8 = *reinterpret_cast<const u16x8*>(&vbase[(size_t)(n0+nl)*C_ + cg*8]);
      #pragma unroll
      for (int j = 0; j < 8; j++) vT[(cg*8+j)*264 + (nl ^ swz)] = v8[j];
    }
    __syncthreads();
    const int arow = wave*16 + fr;
    const int aswz = (arow >> 3) << 3;
    for (int kk = 0; kk < NC_/32; kk++){
      int ko = kk*32 + quad*8;
      bfrag af = *reinterpret_cast<const bfrag*>(&kfT[arow*264 + (ko ^ aswz)]);
      #pragma unroll
      for (int j = 0; j < 5; j++){
        const int brow = j*16 + fr;
        const int bswz = (brow >> 3) << 3;
        bfrag bfr = *reinterpret_cast<const bfrag*>(&vT[brow*264 + (ko ^ bswz)]);
        acc[j] = __builtin_amdgcn_mfma_f32_16x16x32_bf16(af, bfr, acc[j], 0, 0, 0);
      }
    }
    __syncthreads();
  }

  // write kvBT (scaled), with d^64 flip for e>=32; rows 64/65 = z-vectors
  const float invN = 1.0f / (float)N_;
  {
    const int dbase = wave*16 + quad*4;
    #pragma unroll
    for (int j = 0; j < 4; j++){
      const int e = j*16 + fr;
      const int dd = (e < 32) ? dbase : (dbase ^ 64);
      ushort4 w4;
      w4.x = f2bfu(acc[j][0] * invN);
      w4.y = f2bfu(acc[j][1] * invN);
      w4.z = f2bfu(acc[j][2] * invN);
      w4.w = f2bfu(acc[j][3] * invN);
      *reinterpret_cast<ushort4*>(&kvBT[e*136 + dd]) = w4;
    }
    if (fr == 0){
      ushort4 wk;
      wk.x = f2bfu(acc[4][0] * invN);
      wk.y = f2bfu(acc[4][1] * invN);
      wk.z = f2bfu(acc[4][2] * invN);
      wk.w = f2bfu(acc[4][3] * invN);
      *reinterpret_cast<ushort4*>(&kvBT[64*136 + dbase]) = wk;          // km[d]
      *reinterpret_cast<ushort4*>(&kvBT[65*136 + (dbase^64)]) = wk;     // km at flipped d
    }
  }
  __syncthreads();

  // phase B: 4 m-chunks of 128 rows (qf staging = pure vector copy)
  const unsigned short* qfg = qf + (size_t)b*N_*768 + h*128;
  float* xabase = xa + (size_t)b*N_*C_ + h*HD_;
  for (int mc = 0; mc < 4; mc++){
    const int m0 = mc * 128;
    for (int it = 0; it < 4; it++){
      int flat = it*512 + tid;
      int cg = flat & 15, nl = flat >> 4;
      *reinterpret_cast<u16x8*>(&qs[nl*136 + cg*8]) =
          *reinterpret_cast<const u16x8*>(&qfg[(size_t)(m0+nl)*768 + cg*8]);
    }
    __syncthreads();
    f32x4 a2[5] = {};
    for (int kk = 0; kk < 4; kk++){
      int ko = kk*32 + quad*8;
      bfrag af = *reinterpret_cast<const bfrag*>(&qs[(wave*16 + fr)*136 + ko]);
      #pragma unroll
      for (int j = 0; j < 5; j++){
        bfrag bfr = *reinterpret_cast<const bfrag*>(&kvBT[(j*16 + fr)*136 + ko]);
        a2[j] = __builtin_amdgcn_mfma_f32_16x16x32_bf16(af, bfr, a2[j], 0, 0, 0);
      }
    }
    #pragma unroll
    for (int r = 0; r < 4; r++){
      const float zsim = __shfl(a2[4][r], quad*16);
      const float zopp = __shfl(a2[4][r], quad*16 + 1);
      const int n = m0 + wave*16 + quad*4 + r;
      #pragma unroll
      for (int j = 0; j < 4; j++){
        const int e = j*16 + fr;
        const float z = (e < 32) ? zsim : zopp;
        xabase[(size_t)n*C_ + e] = a2[j][r] / (z + 1e-6f);
      }
    }
    __syncthreads();   // before next m-chunk overwrites qs
  }
}

// ---------------- conv: 16 ch/block (grid 192x4, 3 blocks/CU), fuses (xa+vc)*g -> ab bf16 ----------------
__global__ __launch_bounds__(512) void conv_kernel(
    const unsigned short* __restrict__ v, const float* __restrict__ dwc_w,
    const float* __restrict__ dwc_b, const float* __restrict__ xa,
    const unsigned short* __restrict__ g, unsigned short* __restrict__ ab)
{
  const int bh = blockIdx.x;
  const int b = bh / H_, h = bh % H_;
  const int ch0 = blockIdx.y * 16;
  __shared__ float vol[16][521];   // 33.3 KB
  __shared__ float wv[16][126];    // 8.1 KB
  __shared__ float wb[16];
  const int tid = threadIdx.x;
  const unsigned short* vbase = v + (size_t)b*N_*C_ + h*HD_;
  const float* xabatch = xa + (size_t)b*N_*C_ + (size_t)h*N_*HD_;
  const unsigned short* gb = g + (size_t)b*N_*C_ + (size_t)h*N_*HD_;
  unsigned short* abb = ab + (size_t)b*N_*C_ + (size_t)h*N_*HD_;

  // stage v: 16 ch x 512 n
  for (int it = 0; it < 16; it++){
    int flat = it*512 + tid;
    int cl = flat & 15, n = flat >> 4;
    vol[cl][n] = bf2f(vbase[(size_t)n*C_ + ch0 + cl]);
  }
  for (int i = tid; i < 16*125; i += 512){
    int ch = i / 125, wi = i - ch*125;
    wv[ch][wi] = dwc_w[(ch0+ch)*125 + wi];
  }
  if (tid < 16) wb[tid] = dwc_b[ch0 + tid];
  __syncthreads();

  for (int t = 0; t < 2; t++){
    const int task = t*512 + tid;
    const int ch = task & 15;
    const int zy = task >> 4;          // 0..63
    const int z = zy >> 3, yc = zy & 7;
    float o[8];
    const float bias = wb[ch];
    #pragma unroll
    for (int xx = 0; xx < 8; xx++) o[xx] = bias;
    #pragma unroll
    for (int kd = 0; kd < 5; kd++){
      const int zz = z + kd - 2;
      if ((unsigned)zz >= 8u) continue;
      #pragma unroll
      for (int kh = 0; kh < 5; kh++){
        const int yy = yc + kh - 2;
        if ((unsigned)yy >= 8u) continue;
        const float* row = &vol[ch][zz*64 + yy*8];
        float rr[8];
        #pragma unroll
        for (int xx = 0; xx < 8; xx++) rr[xx] = row[xx];
        const float* wrow = &wv[ch][kd*25 + kh*5];
        float w5[5];
        #pragma unroll
        for (int kw = 0; kw < 5; kw++) w5[kw] = wrow[kw];
        #pragma unroll
        for (int xx = 0; xx < 8; xx++){
          #pragma unroll
          for (int kw = 0; kw < 5; kw++){
            const int xi = xx + kw - 2;
            if ((unsigned)xi < 8u) o[xx] = fmaf(w5[kw], rr[xi], o[xx]);
          }
        }
      }
    }
    const int nb = zy * 8;
    #pragma unroll
    for (int xx = 0; xx < 8; xx++){
      const size_t di = (size_t)(nb + xx)*HD_ + ch0 + ch;
      abb[di] = f2bfu((xabatch[di] + o[xx]) * bf2f(gb[di]));   // coalesced (ch fastest)
    }
  }
}

// ---------------- proj GEMM: m97 structure over bf16 ab/Wpb ----------------
__global__ __launch_bounds__(256,4) void proj_kernel(
    const unsigned short* __restrict__ ab, const unsigned short* __restrict__ Wpb,
    const float* __restrict__ bp, float* __restrict__ out)
{
  __shared__ unsigned short As[2][4096];
  __shared__ unsigned short Bs[2][4096];

  const int tid  = threadIdx.x;
  const int row0 = blockIdx.y * 128;
  const int col0 = blockIdx.x * 128;
  const int wave = tid >> 6, lane = tid & 63;
  const int wm = (wave >> 1) * 64, wn = (wave & 1) * 64;
  const int fr = lane & 15, quad = lane >> 4;
  const int srr = tid >> 2;
  const int skc = (tid & 3) * 8;

  const unsigned short* ga0 = &ab[(size_t)(row0 + srr)*C_ + skc];
  const unsigned short* gb0 = &Wpb[(size_t)(col0 + srr)*C_ + skc];
  const size_t gstep = (size_t)64*C_;

  f32x4 acc[4][4] = {};

  gload_lds16(ga0,         &As[0][tid*8]);
  gload_lds16(ga0 + gstep, &As[0][2048 + tid*8]);
  gload_lds16(gb0,         &Bs[0][tid*8]);
  gload_lds16(gb0 + gstep, &Bs[0][2048 + tid*8]);
  __syncthreads();

  #pragma unroll 2
  for (int t = 0; t < 12; t++){
    const int cur = t & 1;
    if (t < 11){
      const int k0 = (t+1)*32;
      gload_lds16(ga0 + k0,         &As[cur^1][tid*8]);
      gload_lds16(ga0 + gstep + k0, &As[cur^1][2048 + tid*8]);
      gload_lds16(gb0 + k0,         &Bs[cur^1][tid*8]);
      gload_lds16(gb0 + gstep + k0, &Bs[cur^1][2048 + tid*8]);
    }
    bfrag af[4], bf[4];
    #pragma unroll
    for (int f = 0; f < 4; f++){
      af[f] = *reinterpret_cast<const bfrag*>(&As[cur][(wm + f*16 + fr)*32 + quad*8]);
      bf[f] = *reinterpret_cast<const bfrag*>(&Bs[cur][(wn + f*16 + fr)*32 + quad*8]);
    }
    #pragma unroll
    for (int i=0;i<4;i++)
      #pragma unroll
      for (int j=0;j<4;j++)
        acc[i][j] = __builtin_amdgcn_mfma_f32_16x16x32_bf16(af[i], bf[j], acc[i][j], 0, 0, 0);
    __syncthreads();
  }

  #pragma unroll
  for (int i = 0; i < 4; i++){
    const int rowb = row0 + wm + i*16 + quad*4;
    #pragma unroll
    for (int j = 0; j < 4; j++){
      const int col = col0 + wn + j*16 + fr;
      const float bcol = bp[col];
      #pragma unroll
      for (int r = 0; r < 4; r++)
        out[(size_t)(rowb + r)*C_ + col] = acc[i][j][r] + bcol;
    }
  }
}

extern "C" void kernel_launch(void* const* d_in, const int* in_sizes, int n_in,
                              void* d_out, int out_size, void* d_ws, size_t ws_size,
                              hipStream_t stream){
  float* out = (float*)d_out;

  const int expect[11] = {6291456, 6291456, 589824, 1536, 147456, 384, 8000, 64, 384, 384, 196608};
  bool ok = (n_in == 11);
  for (int i = 0; ok && i < 11; i++) ok = (in_sizes[i] == expect[i]);
  if (!ok){
    sentinel_kernel<<<(out_size+255)/256, 256, 0, stream>>>(out, out_size);
    return;
  }

  const float* x    = (const float*)d_in[0];
  const float* y    = (const float*)d_in[1];
  const float* W    = (const float*)d_in[2];
  const float* bq   = (const float*)d_in[3];
  const float* Wp   = (const float*)d_in[4];
  const float* bp   = (const float*)d_in[5];
  const float* dwcw = (const float*)d_in[6];
  const float* dwcb = (const float*)d_in[7];
  const float* pwp  = (const float*)d_in[8];
  const float* scp  = (const float*)d_in[9];
  const float* pe   = (const float*)d_in[10];

  float* ws = (float*)d_ws;
  const size_t SZ = (size_t)M_ * C_;   // 6,291,456
  // Lifetime-aliased layout (float units). qf/kf are M*768 ushorts = SZ floats EACH.
  //   qf  [0, SZ)          (2*SZ ushorts)        — dead after attn
  //   kf  [SZ, 2SZ)        (2*SZ ushorts)        — dead after attn
  //   v   [2SZ, 2.5SZ)     (SZ ushorts)
  //   g   [2.5SZ, 3SZ)     (SZ ushorts)
  //   xb  [3SZ, 3.5SZ) yb [3.5SZ, 4SZ)           — dead after gemm
  //   xa  [3SZ, 4SZ) f32                         — aliases xb/yb, written by attn
  //   ab  [0, 0.5SZ)       (SZ ushorts)          — aliases qf, written by conv
  //   Wb  [4SZ, +294912) Wpb (+73728) params
  unsigned short* qf  = (unsigned short*)ws;              // 2*SZ ushorts
  unsigned short* kfb = qf + 2*SZ;                        // 2*SZ ushorts
  unsigned short* v   = (unsigned short*)(ws + 2*SZ);     // SZ ushorts
  unsigned short* g   = v + SZ;                           // SZ ushorts
  unsigned short* xb  = (unsigned short*)(ws + 3*SZ);     // SZ ushorts
  unsigned short* yb  = xb + SZ;                          // SZ ushorts
  float* xa = ws + 3*SZ;                                  // aliases xb/yb (post-gemm)
  unsigned short* ab  = (unsigned short*)ws;              // aliases qf (post-attn)
  unsigned short* Wb  = (unsigned short*)(ws + 4*SZ);     // 589824 ushorts
  unsigned short* Wpb = Wb + 589824;                      // 147456 ushorts
  float* scale_inv = (float*)(Wpb + 147456);
  float* power     = scale_inv + 512;

  param_kernel<<<1, 512, 0, stream>>>(scp, pwp, scale_inv, power);
  cvt_bf16_kernel<<<6504, 256, 0, stream>>>(x, y, W, Wp, xb, yb, Wb, Wpb);
  gemm_qkvg<<<dim3(12, 128), 256, 0, stream>>>(xb, yb, Wb, bq, pe, scale_inv, power, qf, kfb, v, g);
  attn_kernel<<<dim3(B_*H_), 512, 0, stream>>>(qf, kfb, v, xa);
  conv_kernel<<<dim3(B_*H_, 4), 512, 0, stream>>>(v, dwcw, dwcb, xa, g, ab);
  proj_kernel<<<dim3(3, 128), 256, 0, stream>>>(ab, Wpb, bp, out);
}

// Round 6
// 239.788 us; speedup vs baseline: 1.3102x; 1.2959x over previous
//
#include <hip/hip_runtime.h>
#include <hip/hip_bf16.h>
#include <math.h>

#define B_  32
#define N_  512
#define C_  384
#define H_  6
#define HD_ 64
#define M_  (B_*N_)   // 16384 rows

typedef __attribute__((ext_vector_type(8))) short bfrag;            // 8 bf16 (4 VGPRs)
typedef __attribute__((ext_vector_type(8))) unsigned short u16x8;   // 8 bf16 loads
typedef __attribute__((ext_vector_type(4))) float f32x4;            // mfma C/D

__device__ __forceinline__ unsigned short f2bfu(float f){
  unsigned int u = __float_as_uint(f);
  u += 0x7fffu + ((u >> 16) & 1u);   // round-to-nearest-even
  return (unsigned short)(u >> 16);
}
__device__ __forceinline__ float bf2f(unsigned short u){
  return __uint_as_float(((unsigned int)u) << 16);
}
__device__ __forceinline__ bfrag cvt8(float4 a, float4 b){
  bfrag r;
  r[0]=(short)f2bfu(a.x); r[1]=(short)f2bfu(a.y); r[2]=(short)f2bfu(a.z); r[3]=(short)f2bfu(a.w);
  r[4]=(short)f2bfu(b.x); r[5]=(short)f2bfu(b.y); r[6]=(short)f2bfu(b.z); r[7]=(short)f2bfu(b.w);
  return r;
}
// async global->LDS, 16B per lane; LDS dest must be wave-uniform base + lane*16
__device__ __forceinline__ void gload_lds16(const unsigned short* gp, unsigned short* lp){
  __builtin_amdgcn_global_load_lds(
      (const __attribute__((address_space(1))) void*)gp,
      (__attribute__((address_space(3))) void*)lp, 16, 0, 0);
}

// ---------------- params ----------------
__global__ void param_kernel(const float* __restrict__ scale_p,
                             const float* __restrict__ power_p,
                             float* __restrict__ scale_inv,
                             float* __restrict__ power){
  int t = threadIdx.x;
  if (t < C_){
    float s  = scale_p[t];
    scale_inv[t] = 1.0f / log1pf(expf(s));   // 1/softplus
  }
  if (t < H_*HD_){
    float p = power_p[t];
    power[t] = 1.0f + 4.0f / (1.0f + expf(-p));
  }
}

__global__ void sentinel_kernel(float* __restrict__ out, int n){
  int i = blockIdx.x*256 + threadIdx.x;
  if (i < n) out[i] = 1.0e9f;
}

// ---------------- bf16 conversion prepass: x, y, W, Wp ----------------
__global__ __launch_bounds__(256) void cvt_bf16_kernel(
    const float* __restrict__ x, const float* __restrict__ y,
    const float* __restrict__ W, const float* __restrict__ Wp,
    unsigned short* __restrict__ xb, unsigned short* __restrict__ yb,
    unsigned short* __restrict__ Wb, unsigned short* __restrict__ Wpb)
{
  const int bid = blockIdx.x;
  const float* src; unsigned short* dst; int base;
  if (bid < 3072)      { src = x;  dst = xb;  base = bid; }
  else if (bid < 6144) { src = y;  dst = yb;  base = bid - 3072; }
  else if (bid < 6432) { src = W;  dst = Wb;  base = bid - 6144; }
  else                 { src = Wp; dst = Wpb; base = bid - 6432; }
  const size_t i0 = ((size_t)base*256 + threadIdx.x)*8;
  float4 a = *reinterpret_cast<const float4*>(src + i0);
  float4 b = *reinterpret_cast<const float4*>(src + i0 + 4);
  *reinterpret_cast<bfrag*>(dst + i0) = cvt8(a, b);
}

// ---------------- fused qkvg GEMM: [16384 x 1536] = A_mode @ Wb^T, bf16 MFMA ----------------
// grid (12, 128): col block 0..11 (mode = bx/3), row block 0..127.
// Modes 0/1: epilogue applies scale (+pe) + power map and writes qf/kf bf16
// [B,N,H,128] with INTERLEAVED feature layout f' = 2*dd + s (s=0 pos, s=1 neg):
// each lane stores one dword (pos|neg<<16) -> 64B contiguous per quad, no LDS
// restage, no extra register liveness. attn translates the sim/opp swap f^64 -> f'^1.
// __launch_bounds__(256,4): keeps VGPR low (r3: 60). r4 showed uncapped=140 VGPR
// (3 blk/CU, 147us); r5 showed restage+cap=spill (267MB hbm, 158us).
__global__ __launch_bounds__(256,4) void gemm_qkvg(
    const unsigned short* __restrict__ xb, const unsigned short* __restrict__ yb,
    const unsigned short* __restrict__ Wb, const float* __restrict__ bias,
    const float* __restrict__ pe, const float* __restrict__ scale_inv,
    const float* __restrict__ power,
    unsigned short* __restrict__ qf, unsigned short* __restrict__ kf,
    unsigned short* __restrict__ v, unsigned short* __restrict__ g)
{
  __shared__ __align__(16) unsigned short smem[16384];  // 32KB: As[2][4096] | Bs[2][4096]

  const int tid  = threadIdx.x;
  const int row0 = blockIdx.y * 128;
  const int col0 = blockIdx.x * 128;       // global col in [0,1536)
  const int mode = blockIdx.x / 3;         // 0:q(y) 1:k 2:v 3:g
  const unsigned short* Ab = (mode == 0) ? yb : xb;

  const int wave = tid >> 6, lane = tid & 63;
  const int wm = (wave >> 1) * 64, wn = (wave & 1) * 64;
  const int fr = lane & 15, quad = lane >> 4;
  const int srr = tid >> 2;                // staging row 0..63
  const int skc = (tid & 3) * 8;           // staging col 0,8,16,24

  const unsigned short* ga0 = &Ab[(size_t)(row0 + srr)*C_ + skc];
  const unsigned short* gb0 = &Wb[(size_t)(col0 + srr)*C_ + skc];
  const size_t gstep = (size_t)64*C_;

  f32x4 acc[4][4] = {};

  // prologue: stage k0=0 into buffer 0
  gload_lds16(ga0,         &smem[tid*8]);
  gload_lds16(ga0 + gstep, &smem[2048 + tid*8]);
  gload_lds16(gb0,         &smem[8192 + tid*8]);
  gload_lds16(gb0 + gstep, &smem[8192 + 2048 + tid*8]);
  __syncthreads();   // drains vmcnt -> buffer 0 ready

  #pragma unroll 2
  for (int t = 0; t < 12; t++){
    const int cur = t & 1;
    if (t < 11){
      const int k0 = (t+1)*32;
      const int nxt = cur^1;
      gload_lds16(ga0 + k0,         &smem[nxt*4096 + tid*8]);
      gload_lds16(ga0 + gstep + k0, &smem[nxt*4096 + 2048 + tid*8]);
      gload_lds16(gb0 + k0,         &smem[8192 + nxt*4096 + tid*8]);
      gload_lds16(gb0 + gstep + k0, &smem[8192 + nxt*4096 + 2048 + tid*8]);
    }
    bfrag af[4], bf[4];
    #pragma unroll
    for (int f = 0; f < 4; f++){
      af[f] = *reinterpret_cast<const bfrag*>(&smem[cur*4096 + (wm + f*16 + fr)*32 + quad*8]);
      bf[f] = *reinterpret_cast<const bfrag*>(&smem[8192 + cur*4096 + (wn + f*16 + fr)*32 + quad*8]);
    }
    #pragma unroll
    for (int i=0;i<4;i++)
      #pragma unroll
      for (int j=0;j<4;j++)
        acc[i][j] = __builtin_amdgcn_mfma_f32_16x16x32_bf16(af[i], bf[j], acc[i][j], 0, 0, 0);
    __syncthreads();   // drains vmcnt (prefetch landed) + all waves done reading cur
  }

  // epilogue (mode uniform per block)
  const int cbase = col0 - mode*384;
  if (mode <= 1){
    unsigned short* dst = (mode == 0) ? qf : kf;
    #pragma unroll
    for (int i = 0; i < 4; i++){
      const int rowb = row0 + wm + i*16 + quad*4;
      #pragma unroll
      for (int j = 0; j < 4; j++){
        const int cl = wn + j*16 + fr;       // 0..127
        const int cc = cbase + cl;           // col within [0,384)
        const int hh = cc >> 6, dd = cc & 63;
        const float bcol = bias[mode*384 + cc];
        const float scv  = scale_inv[cc];
        const float p    = power[cc];
        #pragma unroll
        for (int r = 0; r < 4; r++){
          const int row = rowb + r;
          float val = acc[i][j][r] + bcol;
          if (mode == 1) val += pe[(row & (N_-1))*C_ + cc];
          val *= scv;
          const float ax = fabsf(val);
          const float pv = (ax > 0.0f) ? exp2f(p * log2f(ax)) : 0.0f;
          const unsigned int pos = f2bfu((val > 0.0f) ? pv : 0.0f);
          const unsigned int neg = f2bfu((val < 0.0f) ? pv : 0.0f);
          // interleaved feature layout: f' = 2*dd + s  -> one coalesced dword
          *reinterpret_cast<unsigned int*>(&dst[(size_t)row*768 + hh*128 + dd*2]) =
              pos | (neg << 16);
        }
      }
    }
  } else {
    unsigned short* dst = (mode == 2) ? v : g;
    #pragma unroll
    for (int i = 0; i < 4; i++){
      const int rowb = row0 + wm + i*16 + quad*4;
      #pragma unroll
      for (int j = 0; j < 4; j++){
        const int cc = cbase + wn + j*16 + fr;
        const float bcol = bias[mode*384 + cc];
        #pragma unroll
        for (int r = 0; r < 4; r++)
          dst[(size_t)(rowb + r)*C_ + cc] = f2bfu(acc[i][j][r] + bcol);
      }
    }
  }
}

// ---------------- attention, MFMA: one block per (b,h), 512 threads (8 waves) ----------------
// qf/kf are precomputed bf16 feature maps [B,N,H,128], feature axis INTERLEAVED
// (f' = 2*dd + s). The sim/opp feature swap (was f^64) is f'^1, applied in the
// kvBT write via pair-swapped ushort4 packs. Phase-A LDS uses XOR col swizzle.
#define NC_ 256
__global__ __launch_bounds__(512) void attn_kernel(
    const unsigned short* __restrict__ qf, const unsigned short* __restrict__ kf,
    const unsigned short* __restrict__ v, float* __restrict__ xa)
{
  const int bh = blockIdx.x;
  const int b = bh / H_, h = bh % H_;
  __shared__ __align__(16) unsigned short smem[54912];  // 109,824 B
  unsigned short* kfT  = smem;                  // [128][264] phase A (col-swizzled)
  unsigned short* vT   = smem + 33792;          // [80][264]  phase A (col-swizzled)
  unsigned short* kvBT = smem;                  // [80][136]  phase B (alias)
  unsigned short* qs   = smem + 33792;          // [128][136] phase B (alias)

  const int tid = threadIdx.x;
  const int wave = tid >> 6, lane = tid & 63;
  const int fr = lane & 15, quad = lane >> 4;

  const unsigned short* kfg   = kf + (size_t)b*N_*768 + h*128;
  const unsigned short* vbase = v  + (size_t)b*N_*C_  + h*HD_;

  // init vT rows 64..79 (ones column + zeros) — constant rows, swizzle-invariant
  for (int i = tid; i < 16*NC_; i += 512){
    int e = 64 + (i >> 8);
    int nl = i & (NC_-1);
    vT[e*264 + nl] = (e == 64) ? (unsigned short)0x3F80 : (unsigned short)0;
  }
  __syncthreads();

  f32x4 acc[5] = {};
  for (int chunk = 0; chunk < 2; chunk++){
    const int n0 = chunk * NC_;
    // kf: 128 f' x 256 nl transpose-copy; store col = nl ^ ((f'>>3)<<3)
    for (int it = 0; it < 8; it++){
      int flat = it*512 + tid;
      int cg = flat & 15, nl = flat >> 4;
      int swz = cg << 3;
      u16x8 k8 = *reinterpret_cast<const u16x8*>(&kfg[(size_t)(n0+nl)*768 + cg*8]);
      #pragma unroll
      for (int j = 0; j < 8; j++) kfT[(cg*8+j)*264 + (nl ^ swz)] = k8[j];
    }
    // v: 64 c x 256 nl
    for (int it = 0; it < 4; it++){
      int flat = it*512 + tid;
      int cg = flat & 7, nl = flat >> 3;
      int swz = cg << 3;
      u16x8 v8 = *reinterpret_cast<const u16x8*>(&vbase[(size_t)(n0+nl)*C_ + cg*8]);
      #pragma unroll
      for (int j = 0; j < 8; j++) vT[(cg*8+j)*264 + (nl ^ swz)] = v8[j];
    }
    __syncthreads();
    const int arow = wave*16 + fr;
    const int aswz = (arow >> 3) << 3;
    for (int kk = 0; kk < NC_/32; kk++){
      int ko = kk*32 + quad*8;
      bfrag af = *reinterpret_cast<const bfrag*>(&kfT[arow*264 + (ko ^ aswz)]);
      #pragma unroll
      for (int j = 0; j < 5; j++){
        const int brow = j*16 + fr;
        const int bswz = (brow >> 3) << 3;
        bfrag bfr = *reinterpret_cast<const bfrag*>(&vT[brow*264 + (ko ^ bswz)]);
        acc[j] = __builtin_amdgcn_mfma_f32_16x16x32_bf16(af, bfr, acc[j], 0, 0, 0);
      }
    }
    __syncthreads();
  }

  // write kvBT (scaled). Rows = v-dims e (0..63) + km rows 64/65; cols = features f'.
  // For e>=32 (opp half) place value of feature f' at column f'^1 (pair swap).
  const float invN = 1.0f / (float)N_;
  {
    const int dbase = wave*16 + quad*4;   // feature base f' (mult of 4)
    #pragma unroll
    for (int j = 0; j < 4; j++){
      const int e = j*16 + fr;            // v-dim
      const unsigned short c0 = f2bfu(acc[j][0] * invN);
      const unsigned short c1 = f2bfu(acc[j][1] * invN);
      const unsigned short c2 = f2bfu(acc[j][2] * invN);
      const unsigned short c3 = f2bfu(acc[j][3] * invN);
      ushort4 w4;
      if (e < 32){ w4.x=c0; w4.y=c1; w4.z=c2; w4.w=c3; }
      else       { w4.x=c1; w4.y=c0; w4.z=c3; w4.w=c2; }   // f'^1 swap
      *reinterpret_cast<ushort4*>(&kvBT[e*136 + dbase]) = w4;
    }
    if (fr == 0){
      const unsigned short k0 = f2bfu(acc[4][0] * invN);
      const unsigned short k1 = f2bfu(acc[4][1] * invN);
      const unsigned short k2 = f2bfu(acc[4][2] * invN);
      const unsigned short k3 = f2bfu(acc[4][3] * invN);
      ushort4 wk;  wk.x=k0;  wk.y=k1;  wk.z=k2;  wk.w=k3;
      ushort4 wkf; wkf.x=k1; wkf.y=k0; wkf.z=k3; wkf.w=k2;
      *reinterpret_cast<ushort4*>(&kvBT[64*136 + dbase]) = wk;    // km[f']   (z_sim)
      *reinterpret_cast<ushort4*>(&kvBT[65*136 + dbase]) = wkf;   // km[f'^1] (z_opp)
    }
  }
  __syncthreads();

  // phase B: 4 m-chunks of 128 rows (qf staging = pure vector copy)
  const unsigned short* qfg = qf + (size_t)b*N_*768 + h*128;
  float* xabase = xa + (size_t)b*N_*C_ + h*HD_;
  for (int mc = 0; mc < 4; mc++){
    const int m0 = mc * 128;
    for (int it = 0; it < 4; it++){
      int flat = it*512 + tid;
      int cg = flat & 15, nl = flat >> 4;
      *reinterpret_cast<u16x8*>(&qs[nl*136 + cg*8]) =
          *reinterpret_cast<const u16x8*>(&qfg[(size_t)(m0+nl)*768 + cg*8]);
    }
    __syncthreads();
    f32x4 a2[5] = {};
    for (int kk = 0; kk < 4; kk++){
      int ko = kk*32 + quad*8;
      bfrag af = *reinterpret_cast<const bfrag*>(&qs[(wave*16 + fr)*136 + ko]);
      #pragma unroll
      for (int j = 0; j < 5; j++){
        bfrag bfr = *reinterpret_cast<const bfrag*>(&kvBT[(j*16 + fr)*136 + ko]);
        a2[j] = __builtin_amdgcn_mfma_f32_16x16x32_bf16(af, bfr, a2[j], 0, 0, 0);
      }
    }
    #pragma unroll
    for (int r = 0; r < 4; r++){
      const float zsim = __shfl(a2[4][r], quad*16);
      const float zopp = __shfl(a2[4][r], quad*16 + 1);
      const int n = m0 + wave*16 + quad*4 + r;
      #pragma unroll
      for (int j = 0; j < 4; j++){
        const int e = j*16 + fr;
        const float z = (e < 32) ? zsim : zopp;
        xabase[(size_t)n*C_ + e] = a2[j][r] / (z + 1e-6f);
      }
    }
    __syncthreads();   // before next m-chunk overwrites qs
  }
}

// ---------------- conv: 16 ch/block (grid 192x4, 3 blocks/CU), fuses (xa+vc)*g -> ab bf16 ----------------
__global__ __launch_bounds__(512) void conv_kernel(
    const unsigned short* __restrict__ v, const float* __restrict__ dwc_w,
    const float* __restrict__ dwc_b, const float* __restrict__ xa,
    const unsigned short* __restrict__ g, unsigned short* __restrict__ ab)
{
  const int bh = blockIdx.x;
  const int b = bh / H_, h = bh % H_;
  const int ch0 = blockIdx.y * 16;
  __shared__ float vol[16][521];   // 33.3 KB
  __shared__ float wv[16][126];    // 8.1 KB
  __shared__ float wb[16];
  const int tid = threadIdx.x;
  const unsigned short* vbase = v + (size_t)b*N_*C_ + h*HD_;
  const float* xabatch = xa + (size_t)b*N_*C_ + (size_t)h*N_*HD_;
  const unsigned short* gb = g + (size_t)b*N_*C_ + (size_t)h*N_*HD_;
  unsigned short* abb = ab + (size_t)b*N_*C_ + (size_t)h*N_*HD_;

  // stage v: 16 ch x 512 n
  for (int it = 0; it < 16; it++){
    int flat = it*512 + tid;
    int cl = flat & 15, n = flat >> 4;
    vol[cl][n] = bf2f(vbase[(size_t)n*C_ + ch0 + cl]);
  }
  for (int i = tid; i < 16*125; i += 512){
    int ch = i / 125, wi = i - ch*125;
    wv[ch][wi] = dwc_w[(ch0+ch)*125 + wi];
  }
  if (tid < 16) wb[tid] = dwc_b[ch0 + tid];
  __syncthreads();

  for (int t = 0; t < 2; t++){
    const int task = t*512 + tid;
    const int ch = task & 15;
    const int zy = task >> 4;          // 0..63
    const int z = zy >> 3, yc = zy & 7;
    float o[8];
    const float bias = wb[ch];
    #pragma unroll
    for (int xx = 0; xx < 8; xx++) o[xx] = bias;
    #pragma unroll
    for (int kd = 0; kd < 5; kd++){
      const int zz = z + kd - 2;
      if ((unsigned)zz >= 8u) continue;
      #pragma unroll
      for (int kh = 0; kh < 5; kh++){
        const int yy = yc + kh - 2;
        if ((unsigned)yy >= 8u) continue;
        const float* row = &vol[ch][zz*64 + yy*8];
        float rr[8];
        #pragma unroll
        for (int xx = 0; xx < 8; xx++) rr[xx] = row[xx];
        const float* wrow = &wv[ch][kd*25 + kh*5];
        float w5[5];
        #pragma unroll
        for (int kw = 0; kw < 5; kw++) w5[kw] = wrow[kw];
        #pragma unroll
        for (int xx = 0; xx < 8; xx++){
          #pragma unroll
          for (int kw = 0; kw < 5; kw++){
            const int xi = xx + kw - 2;
            if ((unsigned)xi < 8u) o[xx] = fmaf(w5[kw], rr[xi], o[xx]);
          }
        }
      }
    }
    const int nb = zy * 8;
    #pragma unroll
    for (int xx = 0; xx < 8; xx++){
      const size_t di = (size_t)(nb + xx)*HD_ + ch0 + ch;
      abb[di] = f2bfu((xabatch[di] + o[xx]) * bf2f(gb[di]));   // coalesced (ch fastest)
    }
  }
}

// ---------------- proj GEMM: m97 structure over bf16 ab/Wpb ----------------
__global__ __launch_bounds__(256,4) void proj_kernel(
    const unsigned short* __restrict__ ab, const unsigned short* __restrict__ Wpb,
    const float* __restrict__ bp, float* __restrict__ out)
{
  __shared__ unsigned short As[2][4096];
  __shared__ unsigned short Bs[2][4096];

  const int tid  = threadIdx.x;
  const int row0 = blockIdx.y * 128;
  const int col0 = blockIdx.x * 128;
  const int wave = tid >> 6, lane = tid & 63;
  const int wm = (wave >> 1) * 64, wn = (wave & 1) * 64;
  const int fr = lane & 15, quad = lane >> 4;
  const int srr = tid >> 2;
  const int skc = (tid & 3) * 8;

  const unsigned short* ga0 = &ab[(size_t)(row0 + srr)*C_ + skc];
  const unsigned short* gb0 = &Wpb[(size_t)(col0 + srr)*C_ + skc];
  const size_t gstep = (size_t)64*C_;

  f32x4 acc[4][4] = {};

  gload_lds16(ga0,         &As[0][tid*8]);
  gload_lds16(ga0 + gstep, &As[0][2048 + tid*8]);
  gload_lds16(gb0,         &Bs[0][tid*8]);
  gload_lds16(gb0 + gstep, &Bs[0][2048 + tid*8]);
  __syncthreads();

  #pragma unroll 2
  for (int t = 0; t < 12; t++){
    const int cur = t & 1;
    if (t < 11){
      const int k0 = (t+1)*32;
      gload_lds16(ga0 + k0,         &As[cur^1][tid*8]);
      gload_lds16(ga0 + gstep + k0, &As[cur^1][2048 + tid*8]);
      gload_lds16(gb0 + k0,         &Bs[cur^1][tid*8]);
      gload_lds16(gb0 + gstep + k0, &Bs[cur^1][2048 + tid*8]);
    }
    bfrag af[4], bf[4];
    #pragma unroll
    for (int f = 0; f < 4; f++){
      af[f] = *reinterpret_cast<const bfrag*>(&As[cur][(wm + f*16 + fr)*32 + quad*8]);
      bf[f] = *reinterpret_cast<const bfrag*>(&Bs[cur][(wn + f*16 + fr)*32 + quad*8]);
    }
    #pragma unroll
    for (int i=0;i<4;i++)
      #pragma unroll
      for (int j=0;j<4;j++)
        acc[i][j] = __builtin_amdgcn_mfma_f32_16x16x32_bf16(af[i], bf[j], acc[i][j], 0, 0, 0);
    __syncthreads();
  }

  #pragma unroll
  for (int i = 0; i < 4; i++){
    const int rowb = row0 + wm + i*16 + quad*4;
    #pragma unroll
    for (int j = 0; j < 4; j++){
      const int col = col0 + wn + j*16 + fr;
      const float bcol = bp[col];
      #pragma unroll
      for (int r = 0; r < 4; r++)
        out[(size_t)(rowb + r)*C_ + col] = acc[i][j][r] + bcol;
    }
  }
}

extern "C" void kernel_launch(void* const* d_in, const int* in_sizes, int n_in,
                              void* d_out, int out_size, void* d_ws, size_t ws_size,
                              hipStream_t stream){
  float* out = (float*)d_out;

  const int expect[11] = {6291456, 6291456, 589824, 1536, 147456, 384, 8000, 64, 384, 384, 196608};
  bool ok = (n_in == 11);
  for (int i = 0; ok && i < 11; i++) ok = (in_sizes[i] == expect[i]);
  if (!ok){
    sentinel_kernel<<<(out_size+255)/256, 256, 0, stream>>>(out, out_size);
    return;
  }

  const float* x    = (const float*)d_in[0];
  const float* y    = (const float*)d_in[1];
  const float* W    = (const float*)d_in[2];
  const float* bq   = (const float*)d_in[3];
  const float* Wp   = (const float*)d_in[4];
  const float* bp   = (const float*)d_in[5];
  const float* dwcw = (const float*)d_in[6];
  const float* dwcb = (const float*)d_in[7];
  const float* pwp  = (const float*)d_in[8];
  const float* scp  = (const float*)d_in[9];
  const float* pe   = (const float*)d_in[10];

  float* ws = (float*)d_ws;
  const size_t SZ = (size_t)M_ * C_;   // 6,291,456
  // Lifetime-aliased layout (float units). qf/kf are M*768 ushorts = SZ floats EACH.
  //   qf  [0, SZ)          (2*SZ ushorts)        — dead after attn
  //   kf  [SZ, 2SZ)        (2*SZ ushorts)        — dead after attn
  //   v   [2SZ, 2.5SZ)     (SZ ushorts)
  //   g   [2.5SZ, 3SZ)     (SZ ushorts)
  //   xb  [3SZ, 3.5SZ) yb [3.5SZ, 4SZ)           — dead after gemm
  //   xa  [3SZ, 4SZ) f32                         — aliases xb/yb, written by attn
  //   ab  [0, 0.5SZ)       (SZ ushorts)          — aliases qf, written by conv
  //   Wb  [4SZ, +294912) Wpb (+73728) params
  unsigned short* qf  = (unsigned short*)ws;              // 2*SZ ushorts
  unsigned short* kfb = qf + 2*SZ;                        // 2*SZ ushorts
  unsigned short* v   = (unsigned short*)(ws + 2*SZ);     // SZ ushorts
  unsigned short* g   = v + SZ;                           // SZ ushorts
  unsigned short* xb  = (unsigned short*)(ws + 3*SZ);     // SZ ushorts
  unsigned short* yb  = xb + SZ;                          // SZ ushorts
  float* xa = ws + 3*SZ;                                  // aliases xb/yb (post-gemm)
  unsigned short* ab  = (unsigned short*)ws;              // aliases qf (post-attn)
  unsigned short* Wb  = (unsigned short*)(ws + 4*SZ);     // 589824 ushorts
  unsigned short* Wpb = Wb + 589824;                      // 147456 ushorts
  float* scale_inv = (float*)(Wpb + 147456);
  float* power     = scale_inv + 512;

  param_kernel<<<1, 512, 0, stream>>>(scp, pwp, scale_inv, power);
  cvt_bf16_kernel<<<6504, 256, 0, stream>>>(x, y, W, Wp, xb, yb, Wb, Wpb);
  gemm_qkvg<<<dim3(12, 128), 256, 0, stream>>>(xb, yb, Wb, bq, pe, scale_inv, power, qf, kfb, v, g);
  attn_kernel<<<dim3(B_*H_), 512, 0, stream>>>(qf, kfb, v, xa);
  conv_kernel<<<dim3(B_*H_, 4), 512, 0, stream>>>(v, dwcw, dwcb, xa, g, ab);
  proj_kernel<<<dim3(3, 128), 256, 0, stream>>>(ab, Wpb, bp, out);
}

// Round 7
// 221.191 us; speedup vs baseline: 1.4204x; 1.0841x over previous
//
#include <hip/hip_runtime.h>
#include <hip/hip_bf16.h>
#include <math.h>

#define B_  32
#define N_  512
#define C_  384
#define H_  6
#define HD_ 64
#define M_  (B_*N_)   // 16384 rows

typedef __attribute__((ext_vector_type(8))) short bfrag;            // 8 bf16 (4 VGPRs)
typedef __attribute__((ext_vector_type(8))) unsigned short u16x8;   // 8 bf16 loads
typedef __attribute__((ext_vector_type(4))) float f32x4;            // mfma C/D

__device__ __forceinline__ unsigned short f2bfu(float f){
  unsigned int u = __float_as_uint(f);
  u += 0x7fffu + ((u >> 16) & 1u);   // round-to-nearest-even
  return (unsigned short)(u >> 16);
}
__device__ __forceinline__ float bf2f(unsigned short u){
  return __uint_as_float(((unsigned int)u) << 16);
}
__device__ __forceinline__ bfrag cvt8(float4 a, float4 b){
  bfrag r;
  r[0]=(short)f2bfu(a.x); r[1]=(short)f2bfu(a.y); r[2]=(short)f2bfu(a.z); r[3]=(short)f2bfu(a.w);
  r[4]=(short)f2bfu(b.x); r[5]=(short)f2bfu(b.y); r[6]=(short)f2bfu(b.z); r[7]=(short)f2bfu(b.w);
  return r;
}
// async global->LDS, 16B per lane; LDS dest must be wave-uniform base + lane*16
__device__ __forceinline__ void gload_lds16(const unsigned short* gp, unsigned short* lp){
  __builtin_amdgcn_global_load_lds(
      (const __attribute__((address_space(1))) void*)gp,
      (__attribute__((address_space(3))) void*)lp, 16, 0, 0);
}

// ---------------- params ----------------
__global__ void param_kernel(const float* __restrict__ scale_p,
                             const float* __restrict__ power_p,
                             float* __restrict__ scale_inv,
                             float* __restrict__ power){
  int t = threadIdx.x;
  if (t < C_){
    float s  = scale_p[t];
    scale_inv[t] = 1.0f / log1pf(expf(s));   // 1/softplus
  }
  if (t < H_*HD_){
    float p = power_p[t];
    power[t] = 1.0f + 4.0f / (1.0f + expf(-p));
  }
}

__global__ void sentinel_kernel(float* __restrict__ out, int n){
  int i = blockIdx.x*256 + threadIdx.x;
  if (i < n) out[i] = 1.0e9f;
}

// ---------------- bf16 conversion prepass: x, y, W, Wp ----------------
__global__ __launch_bounds__(256) void cvt_bf16_kernel(
    const float* __restrict__ x, const float* __restrict__ y,
    const float* __restrict__ W, const float* __restrict__ Wp,
    unsigned short* __restrict__ xb, unsigned short* __restrict__ yb,
    unsigned short* __restrict__ Wb, unsigned short* __restrict__ Wpb)
{
  const int bid = blockIdx.x;
  const float* src; unsigned short* dst; int base;
  if (bid < 3072)      { src = x;  dst = xb;  base = bid; }
  else if (bid < 6144) { src = y;  dst = yb;  base = bid - 3072; }
  else if (bid < 6432) { src = W;  dst = Wb;  base = bid - 6144; }
  else                 { src = Wp; dst = Wpb; base = bid - 6432; }
  const size_t i0 = ((size_t)base*256 + threadIdx.x)*8;
  float4 a = *reinterpret_cast<const float4*>(src + i0);
  float4 b = *reinterpret_cast<const float4*>(src + i0 + 4);
  *reinterpret_cast<bfrag*>(dst + i0) = cvt8(a, b);
}

// ---------------- fused qkvg GEMM: [16384 x 1536] = A_mode @ Wb^T, bf16 MFMA ----------------
// grid (12, 128) with XCD-chunked swizzle: the 12 col-blocks sharing an A-panel
// land on the SAME XCD L2 (was: round-robin -> 8x panel re-fetch, FETCH 71MB vs 28 ideal).
// Modes 0/1: epilogue applies scale (+pe) + power map, interleaved feature layout
// f' = 2*dd + s -> one coalesced dword per lane (r6: WRITE at ideal 75.5MB).
__global__ __launch_bounds__(256,4) void gemm_qkvg(
    const unsigned short* __restrict__ xb, const unsigned short* __restrict__ yb,
    const unsigned short* __restrict__ Wb, const float* __restrict__ bias,
    const float* __restrict__ pe, const float* __restrict__ scale_inv,
    const float* __restrict__ power,
    unsigned short* __restrict__ qf, unsigned short* __restrict__ kf,
    unsigned short* __restrict__ v, unsigned short* __restrict__ g)
{
  __shared__ __align__(16) unsigned short smem[16384];  // 32KB: As[2][4096] | Bs[2][4096]

  const int tid  = threadIdx.x;
  // XCD-chunked bijective swizzle (1536 = 8 * 192): each XCD gets 16 full row-panels
  const int bid0 = blockIdx.y * 12 + blockIdx.x;
  const int nb   = (bid0 & 7) * 192 + (bid0 >> 3);
  const int by   = nb / 12;
  const int bx   = nb - by * 12;
  const int row0 = by * 128;
  const int col0 = bx * 128;               // global col in [0,1536)
  const int mode = bx / 3;                 // 0:q(y) 1:k 2:v 3:g
  const unsigned short* Ab = (mode == 0) ? yb : xb;

  const int wave = tid >> 6, lane = tid & 63;
  const int wm = (wave >> 1) * 64, wn = (wave & 1) * 64;
  const int fr = lane & 15, quad = lane >> 4;
  const int srr = tid >> 2;                // staging row 0..63
  const int skc = (tid & 3) * 8;           // staging col 0,8,16,24

  const unsigned short* ga0 = &Ab[(size_t)(row0 + srr)*C_ + skc];
  const unsigned short* gb0 = &Wb[(size_t)(col0 + srr)*C_ + skc];
  const size_t gstep = (size_t)64*C_;

  f32x4 acc[4][4] = {};

  // prologue: stage k0=0 into buffer 0
  gload_lds16(ga0,         &smem[tid*8]);
  gload_lds16(ga0 + gstep, &smem[2048 + tid*8]);
  gload_lds16(gb0,         &smem[8192 + tid*8]);
  gload_lds16(gb0 + gstep, &smem[8192 + 2048 + tid*8]);
  __syncthreads();   // drains vmcnt -> buffer 0 ready

  #pragma unroll 2
  for (int t = 0; t < 12; t++){
    const int cur = t & 1;
    if (t < 11){
      const int k0 = (t+1)*32;
      const int nxt = cur^1;
      gload_lds16(ga0 + k0,         &smem[nxt*4096 + tid*8]);
      gload_lds16(ga0 + gstep + k0, &smem[nxt*4096 + 2048 + tid*8]);
      gload_lds16(gb0 + k0,         &smem[8192 + nxt*4096 + tid*8]);
      gload_lds16(gb0 + gstep + k0, &smem[8192 + nxt*4096 + 2048 + tid*8]);
    }
    bfrag af[4], bf[4];
    #pragma unroll
    for (int f = 0; f < 4; f++){
      af[f] = *reinterpret_cast<const bfrag*>(&smem[cur*4096 + (wm + f*16 + fr)*32 + quad*8]);
      bf[f] = *reinterpret_cast<const bfrag*>(&smem[8192 + cur*4096 + (wn + f*16 + fr)*32 + quad*8]);
    }
    #pragma unroll
    for (int i=0;i<4;i++)
      #pragma unroll
      for (int j=0;j<4;j++)
        acc[i][j] = __builtin_amdgcn_mfma_f32_16x16x32_bf16(af[i], bf[j], acc[i][j], 0, 0, 0);
    __syncthreads();   // drains vmcnt (prefetch landed) + all waves done reading cur
  }

  // epilogue (mode uniform per block)
  const int cbase = col0 - mode*384;
  if (mode <= 1){
    unsigned short* dst = (mode == 0) ? qf : kf;
    #pragma unroll
    for (int i = 0; i < 4; i++){
      const int rowb = row0 + wm + i*16 + quad*4;
      #pragma unroll
      for (int j = 0; j < 4; j++){
        const int cl = wn + j*16 + fr;       // 0..127
        const int cc = cbase + cl;           // col within [0,384)
        const int hh = cc >> 6, dd = cc & 63;
        const float bcol = bias[mode*384 + cc];
        const float scv  = scale_inv[cc];
        const float p    = power[cc];
        #pragma unroll
        for (int r = 0; r < 4; r++){
          const int row = rowb + r;
          float val = acc[i][j][r] + bcol;
          if (mode == 1) val += pe[(row & (N_-1))*C_ + cc];
          val *= scv;
          const float ax = fabsf(val);
          const float pv = (ax > 0.0f) ? exp2f(p * log2f(ax)) : 0.0f;
          const unsigned int pos = f2bfu((val > 0.0f) ? pv : 0.0f);
          const unsigned int neg = f2bfu((val < 0.0f) ? pv : 0.0f);
          // interleaved feature layout: f' = 2*dd + s  -> one coalesced dword
          *reinterpret_cast<unsigned int*>(&dst[(size_t)row*768 + hh*128 + dd*2]) =
              pos | (neg << 16);
        }
      }
    }
  } else {
    unsigned short* dst = (mode == 2) ? v : g;
    #pragma unroll
    for (int i = 0; i < 4; i++){
      const int rowb = row0 + wm + i*16 + quad*4;
      #pragma unroll
      for (int j = 0; j < 4; j++){
        const int cc = cbase + wn + j*16 + fr;
        const float bcol = bias[mode*384 + cc];
        #pragma unroll
        for (int r = 0; r < 4; r++)
          dst[(size_t)(rowb + r)*C_ + cc] = f2bfu(acc[i][j][r] + bcol);
      }
    }
  }
}

// ---------------- attention, MFMA: one block per (b,h), 512 threads (8 waves) ----------------
// qf/kf bf16 feature maps [B,N,H,128], interleaved f' = 2*dd+s (sim/opp swap = f'^1).
// Phase A: register double-buffered staging (T14) + XOR-swizzled transpose LDS.
// Phase B: NO LDS staging for A — fragments load directly from global (q rows are
// MFMA A-rows); kvBT col-XOR-swizzled (was 8-way bank conflict); no per-mc barriers.
#define NC_ 256
__global__ __launch_bounds__(512) void attn_kernel(
    const unsigned short* __restrict__ qf, const unsigned short* __restrict__ kf,
    const unsigned short* __restrict__ v, float* __restrict__ xa)
{
  const int bh = blockIdx.x;
  const int b = bh / H_, h = bh % H_;
  __shared__ __align__(16) unsigned short smem[54912];  // 109,824 B
  unsigned short* kfT  = smem;                  // [128][264] phase A (col-swizzled)
  unsigned short* vT   = smem + 33792;          // [80][264]  phase A (col-swizzled)
  unsigned short* kvBT = smem;                  // [80][136]  phase B (alias, col-swizzled)

  const int tid = threadIdx.x;
  const int wave = tid >> 6, lane = tid & 63;
  const int fr = lane & 15, quad = lane >> 4;

  const unsigned short* kfg   = kf + (size_t)b*N_*768 + h*128;
  const unsigned short* vbase = v  + (size_t)b*N_*C_  + h*HD_;

  // init vT rows 64..79 (ones column + zeros) — constant rows, swizzle-invariant
  for (int i = tid; i < 16*NC_; i += 512){
    int e = 64 + (i >> 8);
    int nl = i & (NC_-1);
    vT[e*264 + nl] = (e == 64) ? (unsigned short)0x3F80 : (unsigned short)0;
  }

  auto storeA = [&](bfrag* kr, bfrag* vr){
    #pragma unroll
    for (int it = 0; it < 8; it++){
      int flat = it*512 + tid; int cg = flat & 15, nl = flat >> 4; int swz = cg << 3;
      #pragma unroll
      for (int j = 0; j < 8; j++) kfT[(cg*8+j)*264 + (nl ^ swz)] = (unsigned short)kr[it][j];
    }
    #pragma unroll
    for (int it = 0; it < 4; it++){
      int flat = it*512 + tid; int cg = flat & 7, nl = flat >> 3; int swz = cg << 3;
      #pragma unroll
      for (int j = 0; j < 8; j++) vT[(cg*8+j)*264 + (nl ^ swz)] = (unsigned short)vr[it][j];
    }
  };
  auto mfmaA = [&](f32x4* acc){
    const int arow = wave*16 + fr;
    const int aswz = (arow >> 3) << 3;
    for (int kk = 0; kk < NC_/32; kk++){
      int ko = kk*32 + quad*8;
      bfrag af = *reinterpret_cast<const bfrag*>(&kfT[arow*264 + (ko ^ aswz)]);
      #pragma unroll
      for (int j = 0; j < 5; j++){
        const int brow = j*16 + fr;
        const int bswz = (brow >> 3) << 3;
        bfrag bfr = *reinterpret_cast<const bfrag*>(&vT[brow*264 + (ko ^ bswz)]);
        acc[j] = __builtin_amdgcn_mfma_f32_16x16x32_bf16(af, bfr, acc[j], 0, 0, 0);
      }
    }
  };

  // ---- phase A: reg double-buffer (load c1 issued before MFMA c0) ----
  bfrag kr0[8], vr0[4], kr1[8], vr1[4];
  #pragma unroll
  for (int it = 0; it < 8; it++){ int flat = it*512 + tid; int cg = flat & 15, nl = flat >> 4;
    kr0[it] = *reinterpret_cast<const bfrag*>(&kfg[(size_t)nl*768 + cg*8]); }
  #pragma unroll
  for (int it = 0; it < 4; it++){ int flat = it*512 + tid; int cg = flat & 7, nl = flat >> 3;
    vr0[it] = *reinterpret_cast<const bfrag*>(&vbase[(size_t)nl*C_ + cg*8]); }
  storeA(kr0, vr0);
  #pragma unroll
  for (int it = 0; it < 8; it++){ int flat = it*512 + tid; int cg = flat & 15, nl = flat >> 4;
    kr1[it] = *reinterpret_cast<const bfrag*>(&kfg[(size_t)(NC_+nl)*768 + cg*8]); }
  #pragma unroll
  for (int it = 0; it < 4; it++){ int flat = it*512 + tid; int cg = flat & 7, nl = flat >> 3;
    vr1[it] = *reinterpret_cast<const bfrag*>(&vbase[(size_t)(NC_+nl)*C_ + cg*8]); }

  __syncthreads();
  f32x4 acc[5] = {};
  mfmaA(acc);
  __syncthreads();
  storeA(kr1, vr1);
  __syncthreads();
  mfmaA(acc);
  __syncthreads();

  // write kvBT (scaled), interleaved features: e>=32 -> pair swap (f'^1);
  // cols XOR-swizzled by ((e>>3)&7)<<3 (km rows 64/65: swz=0 automatically).
  const float invN = 1.0f / (float)N_;
  {
    const int dbase = wave*16 + quad*4;   // feature base f' (mult of 4)
    #pragma unroll
    for (int j = 0; j < 4; j++){
      const int e = j*16 + fr;            // v-dim
      const unsigned short c0 = f2bfu(acc[j][0] * invN);
      const unsigned short c1 = f2bfu(acc[j][1] * invN);
      const unsigned short c2 = f2bfu(acc[j][2] * invN);
      const unsigned short c3 = f2bfu(acc[j][3] * invN);
      ushort4 w4;
      if (e < 32){ w4.x=c0; w4.y=c1; w4.z=c2; w4.w=c3; }
      else       { w4.x=c1; w4.y=c0; w4.z=c3; w4.w=c2; }   // f'^1 swap
      const int col = dbase ^ (((e >> 3) & 7) << 3);
      *reinterpret_cast<ushort4*>(&kvBT[e*136 + col]) = w4;
    }
    if (fr == 0){
      const unsigned short k0 = f2bfu(acc[4][0] * invN);
      const unsigned short k1 = f2bfu(acc[4][1] * invN);
      const unsigned short k2 = f2bfu(acc[4][2] * invN);
      const unsigned short k3 = f2bfu(acc[4][3] * invN);
      ushort4 wk;  wk.x=k0;  wk.y=k1;  wk.z=k2;  wk.w=k3;
      ushort4 wkf; wkf.x=k1; wkf.y=k0; wkf.z=k3; wkf.w=k2;
      *reinterpret_cast<ushort4*>(&kvBT[64*136 + dbase]) = wk;    // km[f']   (z_sim)
      *reinterpret_cast<ushort4*>(&kvBT[65*136 + dbase]) = wkf;   // km[f'^1] (z_opp)
    }
  }
  __syncthreads();

  // ---- phase B: direct global A-fragments, double-buffered; no barriers ----
  const unsigned short* qfg = qf + (size_t)b*N_*768 + h*128;
  float* xabase = xa + (size_t)b*N_*C_ + h*HD_;
  const int qrow = wave*16 + fr;        // lane's q-row within each 128-chunk
  bfrag qv0[4], qv1[4];
  #pragma unroll
  for (int kk = 0; kk < 4; kk++)
    qv0[kk] = *reinterpret_cast<const bfrag*>(&qfg[(size_t)qrow*768 + kk*32 + quad*8]);

  #pragma unroll
  for (int mc = 0; mc < 4; mc++){
    bfrag* qcur = (mc & 1) ? qv1 : qv0;
    bfrag* qnxt = (mc & 1) ? qv0 : qv1;
    if (mc < 3){
      const int m1 = (mc+1) * 128;
      #pragma unroll
      for (int kk = 0; kk < 4; kk++)
        qnxt[kk] = *reinterpret_cast<const bfrag*>(&qfg[(size_t)(m1+qrow)*768 + kk*32 + quad*8]);
    }
    f32x4 a2[5] = {};
    #pragma unroll
    for (int kk = 0; kk < 4; kk++){
      int ko = kk*32 + quad*8;
      #pragma unroll
      for (int j = 0; j < 5; j++){
        const int brow = j*16 + fr;
        const int bsz = ((brow >> 3) & 7) << 3;
        bfrag bfr = *reinterpret_cast<const bfrag*>(&kvBT[brow*136 + (ko ^ bsz)]);
        a2[j] = __builtin_amdgcn_mfma_f32_16x16x32_bf16(qcur[kk], bfr, a2[j], 0, 0, 0);
      }
    }
    const int m0 = mc * 128;
    #pragma unroll
    for (int r = 0; r < 4; r++){
      const float zsim = __shfl(a2[4][r], quad*16);
      const float zopp = __shfl(a2[4][r], quad*16 + 1);
      const int n = m0 + wave*16 + quad*4 + r;
      #pragma unroll
      for (int j = 0; j < 4; j++){
        const int e = j*16 + fr;
        const float z = (e < 32) ? zsim : zopp;
        xabase[(size_t)n*C_ + e] = a2[j][r] / (z + 1e-6f);
      }
    }
  }
}

// ---------------- conv: 16 ch/block (grid 192x4), vectorized staging, fuses (xa+vc)*g -> ab bf16 ----------------
__global__ __launch_bounds__(512) void conv_kernel(
    const unsigned short* __restrict__ v, const float* __restrict__ dwc_w,
    const float* __restrict__ dwc_b, const float* __restrict__ xa,
    const unsigned short* __restrict__ g, unsigned short* __restrict__ ab)
{
  const int bh = blockIdx.x;
  const int b = bh / H_, h = bh % H_;
  const int ch0 = blockIdx.y * 16;
  __shared__ float vol[16][521];   // 33.3 KB
  __shared__ float wv[16][126];    // 8.1 KB
  __shared__ float wb[16];
  const int tid = threadIdx.x;
  const unsigned short* vbase = v + (size_t)b*N_*C_ + h*HD_;
  const float* xabatch = xa + (size_t)b*N_*C_ + (size_t)h*N_*HD_;
  const unsigned short* gb = g + (size_t)b*N_*C_ + (size_t)h*N_*HD_;
  unsigned short* abb = ab + (size_t)b*N_*C_ + (size_t)h*N_*HD_;

  // stage v: 512 n x 16 ch — vectorized u16x8 reads, transpose into vol[ch][n]
  #pragma unroll
  for (int it = 0; it < 2; it++){
    int flat = it*512 + tid;
    int co = flat & 1, n = flat >> 1;
    u16x8 v8 = *reinterpret_cast<const u16x8*>(&vbase[(size_t)n*C_ + ch0 + co*8]);
    #pragma unroll
    for (int j = 0; j < 8; j++) vol[co*8+j][n] = bf2f(v8[j]);
  }
  for (int i = tid; i < 16*125; i += 512){
    int ch = i / 125, wi = i - ch*125;
    wv[ch][wi] = dwc_w[(ch0+ch)*125 + wi];
  }
  if (tid < 16) wb[tid] = dwc_b[ch0 + tid];
  __syncthreads();

  for (int t = 0; t < 2; t++){
    const int task = t*512 + tid;
    const int ch = task & 15;
    const int zy = task >> 4;          // 0..63
    const int z = zy >> 3, yc = zy & 7;
    float o[8];
    const float bias = wb[ch];
    #pragma unroll
    for (int xx = 0; xx < 8; xx++) o[xx] = bias;
    #pragma unroll
    for (int kd = 0; kd < 5; kd++){
      const int zz = z + kd - 2;
      if ((unsigned)zz >= 8u) continue;
      #pragma unroll
      for (int kh = 0; kh < 5; kh++){
        const int yy = yc + kh - 2;
        if ((unsigned)yy >= 8u) continue;
        const float* row = &vol[ch][zz*64 + yy*8];
        float rr[8];
        #pragma unroll
        for (int xx = 0; xx < 8; xx++) rr[xx] = row[xx];
        const float* wrow = &wv[ch][kd*25 + kh*5];
        float w5[5];
        #pragma unroll
        for (int kw = 0; kw < 5; kw++) w5[kw] = wrow[kw];
        #pragma unroll
        for (int xx = 0; xx < 8; xx++){
          #pragma unroll
          for (int kw = 0; kw < 5; kw++){
            const int xi = xx + kw - 2;
            if ((unsigned)xi < 8u) o[xx] = fmaf(w5[kw], rr[xi], o[xx]);
          }
        }
      }
    }
    const int nb = zy * 8;
    #pragma unroll
    for (int xx = 0; xx < 8; xx++){
      const size_t di = (size_t)(nb + xx)*HD_ + ch0 + ch;
      abb[di] = f2bfu((xabatch[di] + o[xx]) * bf2f(gb[di]));   // coalesced (ch fastest)
    }
  }
}

// ---------------- proj GEMM: m97 structure over bf16 ab/Wpb, XCD-swizzled ----------------
__global__ __launch_bounds__(256,4) void proj_kernel(
    const unsigned short* __restrict__ ab, const unsigned short* __restrict__ Wpb,
    const float* __restrict__ bp, float* __restrict__ out)
{
  __shared__ unsigned short As[2][4096];
  __shared__ unsigned short Bs[2][4096];

  const int tid  = threadIdx.x;
  // XCD-chunked bijective swizzle (384 = 8 * 48)
  const int bid0 = blockIdx.y * 3 + blockIdx.x;
  const int nb   = (bid0 & 7) * 48 + (bid0 >> 3);
  const int by   = nb / 3;
  const int bx   = nb - by * 3;
  const int row0 = by * 128;
  const int col0 = bx * 128;
  const int wave = tid >> 6, lane = tid & 63;
  const int wm = (wave >> 1) * 64, wn = (wave & 1) * 64;
  const int fr = lane & 15, quad = lane >> 4;
  const int srr = tid >> 2;
  const int skc = (tid & 3) * 8;

  const unsigned short* ga0 = &ab[(size_t)(row0 + srr)*C_ + skc];
  const unsigned short* gb0 = &Wpb[(size_t)(col0 + srr)*C_ + skc];
  const size_t gstep = (size_t)64*C_;

  f32x4 acc[4][4] = {};

  gload_lds16(ga0,         &As[0][tid*8]);
  gload_lds16(ga0 + gstep, &As[0][2048 + tid*8]);
  gload_lds16(gb0,         &Bs[0][tid*8]);
  gload_lds16(gb0 + gstep, &Bs[0][2048 + tid*8]);
  __syncthreads();

  #pragma unroll 2
  for (int t = 0; t < 12; t++){
    const int cur = t & 1;
    if (t < 11){
      const int k0 = (t+1)*32;
      gload_lds16(ga0 + k0,         &As[cur^1][tid*8]);
      gload_lds16(ga0 + gstep + k0, &As[cur^1][2048 + tid*8]);
      gload_lds16(gb0 + k0,         &Bs[cur^1][tid*8]);
      gload_lds16(gb0 + gstep + k0, &Bs[cur^1][2048 + tid*8]);
    }
    bfrag af[4], bf[4];
    #pragma unroll
    for (int f = 0; f < 4; f++){
      af[f] = *reinterpret_cast<const bfrag*>(&As[cur][(wm + f*16 + fr)*32 + quad*8]);
      bf[f] = *reinterpret_cast<const bfrag*>(&Bs[cur][(wn + f*16 + fr)*32 + quad*8]);
    }
    #pragma unroll
    for (int i=0;i<4;i++)
      #pragma unroll
      for (int j=0;j<4;j++)
        acc[i][j] = __builtin_amdgcn_mfma_f32_16x16x32_bf16(af[i], bf[j], acc[i][j], 0, 0, 0);
    __syncthreads();
  }

  #pragma unroll
  for (int i = 0; i < 4; i++){
    const int rowb = row0 + wm + i*16 + quad*4;
    #pragma unroll
    for (int j = 0; j < 4; j++){
      const int col = col0 + wn + j*16 + fr;
      const float bcol = bp[col];
      #pragma unroll
      for (int r = 0; r < 4; r++)
        out[(size_t)(rowb + r)*C_ + col] = acc[i][j][r] + bcol;
    }
  }
}

extern "C" void kernel_launch(void* const* d_in, const int* in_sizes, int n_in,
                              void* d_out, int out_size, void* d_ws, size_t ws_size,
                              hipStream_t stream){
  float* out = (float*)d_out;

  const int expect[11] = {6291456, 6291456, 589824, 1536, 147456, 384, 8000, 64, 384, 384, 196608};
  bool ok = (n_in == 11);
  for (int i = 0; ok && i < 11; i++) ok = (in_sizes[i] == expect[i]);
  if (!ok){
    sentinel_kernel<<<(out_size+255)/256, 256, 0, stream>>>(out, out_size);
    return;
  }

  const float* x    = (const float*)d_in[0];
  const float* y    = (const float*)d_in[1];
  const float* W    = (const float*)d_in[2];
  const float* bq   = (const float*)d_in[3];
  const float* Wp   = (const float*)d_in[4];
  const float* bp   = (const float*)d_in[5];
  const float* dwcw = (const float*)d_in[6];
  const float* dwcb = (const float*)d_in[7];
  const float* pwp  = (const float*)d_in[8];
  const float* scp  = (const float*)d_in[9];
  const float* pe   = (const float*)d_in[10];

  float* ws = (float*)d_ws;
  const size_t SZ = (size_t)M_ * C_;   // 6,291,456
  // Lifetime-aliased layout (float units). qf/kf are M*768 ushorts = SZ floats EACH.
  //   qf  [0, SZ)          (2*SZ ushorts)        — dead after attn
  //   kf  [SZ, 2SZ)        (2*SZ ushorts)        — dead after attn
  //   v   [2SZ, 2.5SZ)     (SZ ushorts)
  //   g   [2.5SZ, 3SZ)     (SZ ushorts)
  //   xb  [3SZ, 3.5SZ) yb [3.5SZ, 4SZ)           — dead after gemm
  //   xa  [3SZ, 4SZ) f32                         — aliases xb/yb, written by attn
  //   ab  [0, 0.5SZ)       (SZ ushorts)          — aliases qf, written by conv
  //   Wb  [4SZ, +294912) Wpb (+73728) params
  unsigned short* qf  = (unsigned short*)ws;              // 2*SZ ushorts
  unsigned short* kfb = qf + 2*SZ;                        // 2*SZ ushorts
  unsigned short* v   = (unsigned short*)(ws + 2*SZ);     // SZ ushorts
  unsigned short* g   = v + SZ;                           // SZ ushorts
  unsigned short* xb  = (unsigned short*)(ws + 3*SZ);     // SZ ushorts
  unsigned short* yb  = xb + SZ;                          // SZ ushorts
  float* xa = ws + 3*SZ;                                  // aliases xb/yb (post-gemm)
  unsigned short* ab  = (unsigned short*)ws;              // aliases qf (post-attn)
  unsigned short* Wb  = (unsigned short*)(ws + 4*SZ);     // 589824 ushorts
  unsigned short* Wpb = Wb + 589824;                      // 147456 ushorts
  float* scale_inv = (float*)(Wpb + 147456);
  float* power     = scale_inv + 512;

  param_kernel<<<1, 512, 0, stream>>>(scp, pwp, scale_inv, power);
  cvt_bf16_kernel<<<6504, 256, 0, stream>>>(x, y, W, Wp, xb, yb, Wb, Wpb);
  gemm_qkvg<<<dim3(12, 128), 256, 0, stream>>>(xb, yb, Wb, bq, pe, scale_inv, power, qf, kfb, v, g);
  attn_kernel<<<dim3(B_*H_), 512, 0, stream>>>(qf, kfb, v, xa);
  conv_kernel<<<dim3(B_*H_, 4), 512, 0, stream>>>(v, dwcw, dwcb, xa, g, ab);
  proj_kernel<<<dim3(3, 128), 256, 0, stream>>>(ab, Wpb, bp, out);
}